// Round 1
// 355.397 us; speedup vs baseline: 1.1134x; 1.1134x over previous
//
#include <hip/hip_runtime.h>
#include <hip/hip_bf16.h>

#define T_SEQ   2048
#define HIDDEN  2048
#define NUM_H   32
#define NUM_KV  8
#define HD      128
#define Q_SIZE  4096
#define QKV_N   6144

typedef __bf16 bf16;
typedef __bf16 bf16x8 __attribute__((ext_vector_type(8)));
typedef __bf16 bf16x4 __attribute__((ext_vector_type(4)));
typedef float  floatx4 __attribute__((ext_vector_type(4)));

#define GLOBAL_AS(p) ((const __attribute__((address_space(1))) void*)(p))
#define LDS_AS(p)    ((__attribute__((address_space(3))) void*)(p))

// ---------------------------------------------------------------------------
// Dtype detection (fp32 vs bf16 inputs). flag=1 => bf16.
// ---------------------------------------------------------------------------
__global__ void detect_dtype(const unsigned short* __restrict__ wq, int* flagp)
{
    const int lane = threadIdx.x;   // 64 threads
    int cnt = 0;
    for (int i = lane; i < 512; i += 64) {
        int ef = (wq[i] >> 7) & 0xFF;
        if (ef >= 90 && ef <= 130) cnt++;
    }
    #pragma unroll
    for (int m = 32; m; m >>= 1) cnt += __shfl_xor(cnt, m);
    if (lane == 0) *flagp = (cnt >= 430) ? 1 : 0;
}

// ---------------------------------------------------------------------------
// Canonicalize all float inputs into bf16 workspace copies.
// ---------------------------------------------------------------------------
__global__ __launch_bounds__(256) void convert_all(
    const void* __restrict__ h, const void* __restrict__ wq,
    const void* __restrict__ wo_, const void* __restrict__ qn,
    const void* __restrict__ kn,
    bf16* __restrict__ hb, bf16* __restrict__ wqb, bf16* __restrict__ wob,
    bf16* __restrict__ qnb, bf16* __restrict__ knb, const int* flagp)
{
    long e = ((long)blockIdx.x * 256 + threadIdx.x) * 8;
    const void* src; bf16* dst; long off;
    if      (e < 4194304)  { src = h;   dst = hb;  off = e; }
    else if (e < 16777216) { src = wq;  dst = wqb; off = e - 4194304; }
    else if (e < 25165824) { src = wo_; dst = wob; off = e - 16777216; }
    else if (e < 25165952) { src = qn;  dst = qnb; off = e - 25165824; }
    else if (e < 25166080) { src = kn;  dst = knb; off = e - 25165952; }
    else return;

    if (*flagp) {
        *(bf16x8*)(dst + off) = *(const bf16x8*)((const bf16*)src + off);
    } else {
        const float* f = (const float*)src + off;
        bf16x8 v;
        #pragma unroll
        for (int i = 0; i < 8; ++i) v[i] = (bf16)f[i];
        *(bf16x8*)(dst + off) = v;
    }
}

// ---------------------------------------------------------------------------
// NT GEMM 128x128 (m97 structure), used for the QKV projection (768 blocks).
// ---------------------------------------------------------------------------
__global__ __launch_bounds__(256) void gemm_bt(
    const bf16* __restrict__ A, const bf16* __restrict__ B,
    void* __restrict__ Cv, int M, int N, int K, int lda,
    const int* flagp, int is_final)
{
    __shared__ bf16 As[128 * 32];
    __shared__ bf16 Bs[128 * 32];

    const int tid  = threadIdx.x;
    const int wave = tid >> 6, lane = tid & 63;
    const int quad = lane >> 4, l16 = lane & 15;
    const int wm = (wave & 1) * 64, wn = (wave >> 1) * 64;
    const long baseM = (long)blockIdx.x * 128;
    const long baseN = (long)blockIdx.y * 128;
    const int  bf_out = is_final ? *flagp : 1;

    const int  srow = wave * 16 + (lane >> 2);
    const int  scol = (lane & 3) * 8;
    const long aoff0 = (baseM + srow) * (long)lda + scol;
    const long aoff1 = (baseM + 64 + srow) * (long)lda + scol;
    const long boff0 = (baseN + srow) * (long)K + scol;
    const long boff1 = (baseN + 64 + srow) * (long)K + scol;
    const int  lds0 = wave * 512;
    const int  lds1 = 2048 + wave * 512;

    floatx4 acc[4][4] = {};

    for (int k0 = 0; k0 < K; k0 += 32) {
        __builtin_amdgcn_global_load_lds(GLOBAL_AS(A + aoff0 + k0), LDS_AS(As + lds0), 16, 0, 0);
        __builtin_amdgcn_global_load_lds(GLOBAL_AS(A + aoff1 + k0), LDS_AS(As + lds1), 16, 0, 0);
        __builtin_amdgcn_global_load_lds(GLOBAL_AS(B + boff0 + k0), LDS_AS(Bs + lds0), 16, 0, 0);
        __builtin_amdgcn_global_load_lds(GLOBAL_AS(B + boff1 + k0), LDS_AS(Bs + lds1), 16, 0, 0);
        __syncthreads();

        bf16x8 af[4], bfr[4];
        #pragma unroll
        for (int i = 0; i < 4; ++i)
            af[i] = *(const bf16x8*)(As + (wm + i * 16 + l16) * 32 + quad * 8);
        #pragma unroll
        for (int j = 0; j < 4; ++j)
            bfr[j] = *(const bf16x8*)(Bs + (wn + j * 16 + l16) * 32 + quad * 8);

        #pragma unroll
        for (int i = 0; i < 4; ++i)
            #pragma unroll
            for (int j = 0; j < 4; ++j)
                acc[i][j] = __builtin_amdgcn_mfma_f32_16x16x32_bf16(af[i], bfr[j], acc[i][j], 0, 0, 0);
        __syncthreads();
    }

    #pragma unroll
    for (int i = 0; i < 4; ++i)
        #pragma unroll
        for (int j = 0; j < 4; ++j)
            #pragma unroll
            for (int r = 0; r < 4; ++r) {
                long row = baseM + wm + i * 16 + quad * 4 + r;
                long col = baseN + wn + j * 16 + l16;
                if (bf_out) ((bf16*)Cv)[row * (long)N + col] = (bf16)acc[i][j][r];
                else       ((float*)Cv)[row * (long)N + col] = acc[i][j][r];
            }
}

// ---------------------------------------------------------------------------
// NT GEMM 128x64 tile — for the o-proj (grid 16x32 = 512 blocks = 2/CU,
// so barrier drains overlap with the co-resident block).
// ---------------------------------------------------------------------------
__global__ __launch_bounds__(256) void gemm_bt64(
    const bf16* __restrict__ A, const bf16* __restrict__ B,
    void* __restrict__ Cv, int M, int N, int K, int lda,
    const int* flagp, int is_final)
{
    __shared__ bf16 As[128 * 32];
    __shared__ bf16 Bs[64 * 32];

    const int tid  = threadIdx.x;
    const int wave = tid >> 6, lane = tid & 63;
    const int quad = lane >> 4, l16 = lane & 15;
    const int wm = (wave & 1) * 64, wn = (wave >> 1) * 32;
    const long baseM = (long)blockIdx.x * 128;
    const long baseN = (long)blockIdx.y * 64;
    const int  bf_out = is_final ? *flagp : 1;

    const int  srow = wave * 16 + (lane >> 2);
    const int  scol = (lane & 3) * 8;
    const long aoff0 = (baseM + srow) * (long)lda + scol;
    const long aoff1 = (baseM + 64 + srow) * (long)lda + scol;
    const long boff0 = (baseN + srow) * (long)K + scol;
    const int  lds0 = wave * 512;
    const int  lds1 = 2048 + wave * 512;

    floatx4 acc[4][2] = {};

    for (int k0 = 0; k0 < K; k0 += 32) {
        __builtin_amdgcn_global_load_lds(GLOBAL_AS(A + aoff0 + k0), LDS_AS(As + lds0), 16, 0, 0);
        __builtin_amdgcn_global_load_lds(GLOBAL_AS(A + aoff1 + k0), LDS_AS(As + lds1), 16, 0, 0);
        __builtin_amdgcn_global_load_lds(GLOBAL_AS(B + boff0 + k0), LDS_AS(Bs + lds0), 16, 0, 0);
        __syncthreads();

        bf16x8 af[4], bfr[2];
        #pragma unroll
        for (int i = 0; i < 4; ++i)
            af[i] = *(const bf16x8*)(As + (wm + i * 16 + l16) * 32 + quad * 8);
        #pragma unroll
        for (int j = 0; j < 2; ++j)
            bfr[j] = *(const bf16x8*)(Bs + (wn + j * 16 + l16) * 32 + quad * 8);

        #pragma unroll
        for (int i = 0; i < 4; ++i)
            #pragma unroll
            for (int j = 0; j < 2; ++j)
                acc[i][j] = __builtin_amdgcn_mfma_f32_16x16x32_bf16(af[i], bfr[j], acc[i][j], 0, 0, 0);
        __syncthreads();
    }

    #pragma unroll
    for (int i = 0; i < 4; ++i)
        #pragma unroll
        for (int j = 0; j < 2; ++j)
            #pragma unroll
            for (int r = 0; r < 4; ++r) {
                long row = baseM + wm + i * 16 + quad * 4 + r;
                long col = baseN + wn + j * 16 + l16;
                if (bf_out) ((bf16*)Cv)[row * (long)N + col] = (bf16)acc[i][j][r];
                else       ((float*)Cv)[row * (long)N + col] = acc[i][j][r];
            }
}

// ---------------------------------------------------------------------------
// In-place RMSNorm + RoPE on q/k sections of qkv[t][6144].
// ---------------------------------------------------------------------------
__global__ __launch_bounds__(256) void qkv_post(
    bf16* __restrict__ qkv, const int* __restrict__ positions,
    const bf16* __restrict__ qnw, const bf16* __restrict__ knw)
{
    const int t = blockIdx.x;
    const int tid = threadIdx.x, wave = tid >> 6, lane = tid & 63;
    const float pos = (float)positions[t];

    const float inv = expf(-(float)lane * (float)(9.210340371976184 / 64.0));
    float sn, cs;
    sincosf(pos * inv, &sn, &cs);

    bf16* row = qkv + (long)t * QKV_N;

    for (int u = wave; u < 40; u += 4) {
        bf16* p       = (u < 32) ? row + u * HD : row + Q_SIZE + (u - 32) * HD;
        const bf16* w = (u < 32) ? qnw : knw;
        float x1 = (float)p[lane], x2 = (float)p[lane + 64];
        float ss = x1 * x1 + x2 * x2;
        #pragma unroll
        for (int m = 32; m; m >>= 1) ss += __shfl_xor(ss, m);
        float rr = rsqrtf(ss * (1.f / 128.f) + 1e-6f);
        float y1 = x1 * rr * (float)w[lane];
        float y2 = x2 * rr * (float)w[lane + 64];
        p[lane]      = (bf16)(y1 * cs - y2 * sn);
        p[lane + 64] = (bf16)(y2 * cs + y1 * sn);
    }
}

// ---------------------------------------------------------------------------
// V transpose: vt[kvh][d][t] from qkv[t][5120+kvh*128+d].
// ---------------------------------------------------------------------------
__global__ __launch_bounds__(256) void vtrans(const bf16* __restrict__ qkv,
                                              bf16* __restrict__ vt)
{
    __shared__ bf16 tile[64][136];
    const int t0 = blockIdx.x * 64, kvh = blockIdx.y, tid = threadIdx.x;

    const int rl = tid >> 4, c8 = (tid & 15) * 8;
    const bf16* src = qkv + (long)t0 * QKV_N + 5120 + kvh * HD;
    #pragma unroll
    for (int it = 0; it < 4; ++it) {
        int r = it * 16 + rl;
        *(bf16x8*)(&tile[r][c8]) = *(const bf16x8*)(src + (long)r * QKV_N + c8);
    }
    __syncthreads();

    const int d = tid >> 1, tb = (tid & 1) * 32;
    bf16* dst = vt + ((long)kvh * HD + d) * T_SEQ + t0 + tb;
    #pragma unroll
    for (int it = 0; it < 4; ++it) {
        bf16x8 v;
        #pragma unroll
        for (int j = 0; j < 8; ++j) v[j] = tile[tb + it * 8 + j][d];
        *(bf16x8*)(dst + it * 8) = v;
    }
}

// ---------------------------------------------------------------------------
// attn5: unpaired 64-row q-tiles, grid (head, 32) with iq = 31 - blockIdx.y
// (LPT: longest tiles dispatch first). 1024 blocks; LDS = 48KB (K dbuf +
// single V) -> 3 blocks/CU = 12 waves/CU (was 2 blocks / 8 waves).
// Two barriers/iter: __syncthreads at top (drains K[p], closes Vs reuse),
// then raw s_barrier + counted vmcnt(4) mid-iter so the K[t+1] prefetch is
// never drained. P goes bf16 fully in-register: K rows are staged with
// quads 1<->2 swapped (sigma) so the P redistribution for the PV A-operand
// is a pure lane+-32 exchange: 8 v_cvt_pk_bf16_f32 + 4 permlane32_swap
// per tile (no Ps LDS round-trip). exp2 via raw v_exp_f32 builtin
// (args bounded in [-35, 0] since fixed-max C2 = 12*log2e).
// ---------------------------------------------------------------------------
__global__ __launch_bounds__(256, 3) void attn5(bf16* qkv, const bf16* __restrict__ vt)
{
    __shared__ bf16 Ks[2][64 * 128];   // [kt-row][d], 16B chunk c at c^(row&15), rows sigma'd
    __shared__ bf16 Vs[128 * 64];      // [d][kt-row], 16B chunk c at c^(d&7), single buffer

    const int tid  = threadIdx.x, wave = tid >> 6, lane = tid & 63;
    const int quad = lane >> 4, l16 = lane & 15;
    const int h = blockIdx.x, kvh = h >> 2;
    const int iq = 31 - blockIdx.y;    // tile index, longest first (LPT)
    const int q0 = iq * 64;

    const float C1 = 0.12753236f;      // 128^-0.5 * log2(e)
    const float C2 = 17.312340f;       // 12 * log2(e)

    // Q fragments (MFMA B-operand)
    bf16x8 qf[4];
    {
        const bf16* qa = qkv + (long)(q0 + wave * 16 + l16) * QKV_N + h * HD + quad * 8;
        #pragma unroll
        for (int ks = 0; ks < 4; ++ks) qf[ks] = *(const bf16x8*)(qa + ks * 32);
    }

    floatx4 oacc[8] = {};
    float ls = 0.f;                    // per-lane partial row sum

    const int krl = lane >> 4, kc = lane & 15;
    const int vrl = lane >> 3, vc = lane & 7;
    const int kswz = (kc ^ (wave * 4 + krl)) * 8;
    const int vswz = (vc ^ (vrl & 7)) * 8;
    const int wsig = ((wave & 1) << 1) | (wave >> 1);           // sigma(wave): 1<->2
    const int sq4  = (((quad & 1) << 1) | (quad >> 1)) << 2;    // sigma(quad)*4

    const bf16* kg0 = qkv + Q_SIZE + kvh * HD;
    const bf16* vg0 = vt + (long)kvh * HD * T_SEQ;

    // K stage: LDS slot row (it*16 + wave*4 + krl) gets GLOBAL row
    // (it*16 + sigma(wave)*4 + krl); chunk swizzle stays slot-row-based.
    auto stageK = [&](int p, int kt) {
        const bf16* kg = kg0 + (long)(kt * 64) * QKV_N;
        #pragma unroll
        for (int it = 0; it < 4; ++it) {
            const int rK = it * 16 + wsig * 4 + krl;
            __builtin_amdgcn_global_load_lds(GLOBAL_AS(kg + (long)rK * QKV_N + kswz),
                                             LDS_AS(&Ks[p][it * 2048 + wave * 512]), 16, 0, 0);
        }
    };
    auto stageV = [&](int kt) {
        const bf16* vg = vg0 + kt * 64;
        #pragma unroll
        for (int it = 0; it < 4; ++it) {
            const int dV = it * 32 + wave * 8 + vrl;
            __builtin_amdgcn_global_load_lds(GLOBAL_AS(vg + (long)dV * T_SEQ + vswz),
                                             LDS_AS(&Vs[it * 2048 + wave * 512]), 16, 0, 0);
        }
    };

    stageK(0, 0);

    const int qg = q0 + wave * 16 + l16;

    for (int kt = 0; kt <= iq; ++kt) {
        const int p = kt & 1;
        __syncthreads();                   // K[p] landed (vmcnt0); all Vs readers done
        stageV(kt);                        // V first (counted-wait relies on FIFO retire)
        if (kt < iq) stageK(p ^ 1, kt + 1);

        const int k0 = kt * 64;

        // S^T = K Q^T (rows = sigma'd kt, cols = q)
        floatx4 sT[4] = {};
        #pragma unroll
        for (int j2 = 0; j2 < 4; ++j2)
            #pragma unroll
            for (int ks = 0; ks < 4; ++ks) {
                bf16x8 kf = *(const bf16x8*)(&Ks[p][(j2 * 16 + l16) * 128 + (((ks * 4 + quad) ^ l16) * 8)]);
                sT[j2] = __builtin_amdgcn_mfma_f32_16x16x32_bf16(kf, qf[ks], sT[j2], 0, 0, 0);
            }

        // softmax numerators, fully in-register: this lane's element (j2,r)
        // is P(q = l16, kt = k0 + j2*16 + sigma(quad)*4 + r)
        const bool diag = (kt == iq);
        unsigned lov[4], hiv[4];
        #pragma unroll
        for (int j2 = 0; j2 < 4; ++j2) {
            float ev[4];
            #pragma unroll
            for (int r = 0; r < 4; ++r) {
                float x = __builtin_amdgcn_exp2f(sT[j2][r] * C1 - C2);
                if (diag && (k0 + j2 * 16 + sq4 + r > qg)) x = 0.f;
                ls += x;
                ev[r] = x;
            }
            asm("v_cvt_pk_bf16_f32 %0, %1, %2" : "=v"(lov[j2]) : "v"(ev[0]), "v"(ev[1]));
            asm("v_cvt_pk_bf16_f32 %0, %1, %2" : "=v"(hiv[j2]) : "v"(ev[2]), "v"(ev[3]));
        }

        // lane+-32 redistribution to PV A-operand layout:
        // pa[ks2] elem j = P(l16, ks2*32 + quad*8 + j)
        bf16x8 pa[2];
        #pragma unroll
        for (int ks2 = 0; ks2 < 2; ++ks2) {
            auto wl = __builtin_amdgcn_permlane32_swap(lov[2 * ks2], lov[2 * ks2 + 1], false, false);
            auto wh = __builtin_amdgcn_permlane32_swap(hiv[2 * ks2], hiv[2 * ks2 + 1], false, false);
            union { unsigned w[4]; bf16x8 v; } u;
            u.w[0] = wl[0]; u.w[1] = wh[0]; u.w[2] = wl[1]; u.w[3] = wh[1];
            pa[ks2] = u.v;
        }

        // mid barrier: V[kt] landed (4 oldest loads retired), K[t+1] stays in flight
        if (kt < iq) asm volatile("s_waitcnt vmcnt(4)" ::: "memory");
        else         asm volatile("s_waitcnt vmcnt(0)" ::: "memory");
        __builtin_amdgcn_s_barrier();
        __builtin_amdgcn_sched_barrier(0);

        // O += P V
        #pragma unroll
        for (int ks2 = 0; ks2 < 2; ++ks2)
            #pragma unroll
            for (int vj = 0; vj < 8; ++vj) {
                const int d = vj * 16 + l16;
                bf16x8 vb = *(const bf16x8*)(&Vs[d * 64 + (((ks2 * 4 + quad) ^ (d & 7)) * 8)]);
                oacc[vj] = __builtin_amdgcn_mfma_f32_16x16x32_bf16(pa[ks2], vb, oacc[vj], 0, 0, 0);
            }
    }

    // total row sums: reduce over quads (lane l16 holds q-row l16's sum)
    ls += __shfl_xor(ls, 16); ls += __shfl_xor(ls, 32);
    float rinv[4];
    #pragma unroll
    for (int r = 0; r < 4; ++r) rinv[r] = 1.f / __shfl(ls, quad * 4 + r);

    #pragma unroll
    for (int vj = 0; vj < 8; ++vj)
        #pragma unroll
        for (int r = 0; r < 4; ++r) {
            const long row = q0 + wave * 16 + quad * 4 + r;
            qkv[row * (long)QKV_N + h * HD + vj * 16 + l16] = (bf16)(oacc[vj][r] * rinv[r]);
        }
}

// ---------------------------------------------------------------------------
extern "C" void kernel_launch(void* const* d_in, const int* in_sizes, int n_in,
                              void* d_out, int out_size, void* d_ws, size_t ws_size,
                              hipStream_t stream)
{
    const int* positions = (const int*)d_in[0];

    char* ws = (char*)d_ws;
    bf16* qkv  = (bf16*)(ws);              // [2048][6144]  25165824 B
    bf16* hb   = (bf16*)(ws + 25165824);   // [2048][2048]   8388608 B (dead after gemm1)
    bf16* vt   = hb;                       // [8][128][2048] 4194304 B (aliases hb)
    bf16* wqb  = (bf16*)(ws + 33554432);   // [6144][2048]  25165824 B
    bf16* wob  = (bf16*)(ws + 58720256);   // [2048][4096]  16777216 B
    bf16* qnb  = (bf16*)(ws + 75497472);
    bf16* knb  = (bf16*)(ws + 75497728);
    int*  flag = (int*) (ws + 75497984);

    detect_dtype<<<dim3(1), dim3(64), 0, stream>>>((const unsigned short*)d_in[2], flag);
    convert_all<<<dim3(12289), dim3(256), 0, stream>>>(
        d_in[1], d_in[2], d_in[3], d_in[4], d_in[5],
        hb, wqb, wob, qnb, knb, flag);

    dim3 blk(256);
    gemm_bt<<<dim3(T_SEQ / 128, QKV_N / 128), blk, 0, stream>>>(
        hb, wqb, qkv, T_SEQ, QKV_N, HIDDEN, HIDDEN, flag, 0);
    vtrans<<<dim3(T_SEQ / 64, NUM_KV), blk, 0, stream>>>(qkv, vt);
    qkv_post<<<dim3(T_SEQ), blk, 0, stream>>>(qkv, positions, qnb, knb);
    attn5<<<dim3(NUM_H, 32), blk, 0, stream>>>(qkv, vt);
    gemm_bt64<<<dim3(T_SEQ / 128, HIDDEN / 64), blk, 0, stream>>>(
        qkv, wob, d_out, T_SEQ, HIDDEN, Q_SIZE, QKV_N, flag, 1);
}

// Round 2
// 342.318 us; speedup vs baseline: 1.1559x; 1.0382x over previous
//
#include <hip/hip_runtime.h>
#include <hip/hip_bf16.h>

#define T_SEQ   2048
#define HIDDEN  2048
#define NUM_H   32
#define NUM_KV  8
#define HD      128
#define Q_SIZE  4096
#define QKV_N   6144

typedef __bf16 bf16;
typedef __bf16 bf16x8 __attribute__((ext_vector_type(8)));
typedef __bf16 bf16x4 __attribute__((ext_vector_type(4)));
typedef float  floatx4 __attribute__((ext_vector_type(4)));

#define GLOBAL_AS(p) ((const __attribute__((address_space(1))) void*)(p))
#define LDS_AS(p)    ((__attribute__((address_space(3))) void*)(p))

// ---------------------------------------------------------------------------
// Dtype detection (fp32 vs bf16 inputs). flag=1 => bf16.
// ---------------------------------------------------------------------------
__global__ void detect_dtype(const unsigned short* __restrict__ wq, int* flagp)
{
    const int lane = threadIdx.x;   // 64 threads
    int cnt = 0;
    for (int i = lane; i < 512; i += 64) {
        int ef = (wq[i] >> 7) & 0xFF;
        if (ef >= 90 && ef <= 130) cnt++;
    }
    #pragma unroll
    for (int m = 32; m; m >>= 1) cnt += __shfl_xor(cnt, m);
    if (lane == 0) *flagp = (cnt >= 430) ? 1 : 0;
}

// ---------------------------------------------------------------------------
// Canonicalize all float inputs into bf16 workspace copies.
// ---------------------------------------------------------------------------
__global__ __launch_bounds__(256) void convert_all(
    const void* __restrict__ h, const void* __restrict__ wq,
    const void* __restrict__ wo_, const void* __restrict__ qn,
    const void* __restrict__ kn,
    bf16* __restrict__ hb, bf16* __restrict__ wqb, bf16* __restrict__ wob,
    bf16* __restrict__ qnb, bf16* __restrict__ knb, const int* flagp)
{
    long e = ((long)blockIdx.x * 256 + threadIdx.x) * 8;
    const void* src; bf16* dst; long off;
    if      (e < 4194304)  { src = h;   dst = hb;  off = e; }
    else if (e < 16777216) { src = wq;  dst = wqb; off = e - 4194304; }
    else if (e < 25165824) { src = wo_; dst = wob; off = e - 16777216; }
    else if (e < 25165952) { src = qn;  dst = qnb; off = e - 25165824; }
    else if (e < 25166080) { src = kn;  dst = knb; off = e - 25165952; }
    else return;

    if (*flagp) {
        *(bf16x8*)(dst + off) = *(const bf16x8*)((const bf16*)src + off);
    } else {
        const float* f = (const float*)src + off;
        bf16x8 v;
        #pragma unroll
        for (int i = 0; i < 8; ++i) v[i] = (bf16)f[i];
        *(bf16x8*)(dst + off) = v;
    }
}

// ---------------------------------------------------------------------------
// NT GEMM 128x128 (m97 structure), used for the QKV projection (768 blocks,
// 3 blocks/CU -> wave-level overlap hides the per-iter drain; dbuf is parity
// at this occupancy per m99/m100, so keep the simple proven structure).
// ---------------------------------------------------------------------------
__global__ __launch_bounds__(256) void gemm_bt(
    const bf16* __restrict__ A, const bf16* __restrict__ B,
    void* __restrict__ Cv, int M, int N, int K, int lda,
    const int* flagp, int is_final)
{
    __shared__ bf16 As[128 * 32];
    __shared__ bf16 Bs[128 * 32];

    const int tid  = threadIdx.x;
    const int wave = tid >> 6, lane = tid & 63;
    const int quad = lane >> 4, l16 = lane & 15;
    const int wm = (wave & 1) * 64, wn = (wave >> 1) * 64;
    const long baseM = (long)blockIdx.x * 128;
    const long baseN = (long)blockIdx.y * 128;
    const int  bf_out = is_final ? *flagp : 1;

    const int  srow = wave * 16 + (lane >> 2);
    const int  scol = (lane & 3) * 8;
    const long aoff0 = (baseM + srow) * (long)lda + scol;
    const long aoff1 = (baseM + 64 + srow) * (long)lda + scol;
    const long boff0 = (baseN + srow) * (long)K + scol;
    const long boff1 = (baseN + 64 + srow) * (long)K + scol;
    const int  lds0 = wave * 512;
    const int  lds1 = 2048 + wave * 512;

    floatx4 acc[4][4] = {};

    for (int k0 = 0; k0 < K; k0 += 32) {
        __builtin_amdgcn_global_load_lds(GLOBAL_AS(A + aoff0 + k0), LDS_AS(As + lds0), 16, 0, 0);
        __builtin_amdgcn_global_load_lds(GLOBAL_AS(A + aoff1 + k0), LDS_AS(As + lds1), 16, 0, 0);
        __builtin_amdgcn_global_load_lds(GLOBAL_AS(B + boff0 + k0), LDS_AS(Bs + lds0), 16, 0, 0);
        __builtin_amdgcn_global_load_lds(GLOBAL_AS(B + boff1 + k0), LDS_AS(Bs + lds1), 16, 0, 0);
        __syncthreads();

        bf16x8 af[4], bfr[4];
        #pragma unroll
        for (int i = 0; i < 4; ++i)
            af[i] = *(const bf16x8*)(As + (wm + i * 16 + l16) * 32 + quad * 8);
        #pragma unroll
        for (int j = 0; j < 4; ++j)
            bfr[j] = *(const bf16x8*)(Bs + (wn + j * 16 + l16) * 32 + quad * 8);

        #pragma unroll
        for (int i = 0; i < 4; ++i)
            #pragma unroll
            for (int j = 0; j < 4; ++j)
                acc[i][j] = __builtin_amdgcn_mfma_f32_16x16x32_bf16(af[i], bfr[j], acc[i][j], 0, 0, 0);
        __syncthreads();
    }

    #pragma unroll
    for (int i = 0; i < 4; ++i)
        #pragma unroll
        for (int j = 0; j < 4; ++j)
            #pragma unroll
            for (int r = 0; r < 4; ++r) {
                long row = baseM + wm + i * 16 + quad * 4 + r;
                long col = baseN + wn + j * 16 + l16;
                if (bf_out) ((bf16*)Cv)[row * (long)N + col] = (bf16)acc[i][j][r];
                else       ((float*)Cv)[row * (long)N + col] = acc[i][j][r];
            }
}

// ---------------------------------------------------------------------------
// gemm_db: NT GEMM 128x128, double-buffered 2-phase (T3-minimum), split-K via
// blockIdx.z. Per K-step: issue STAGE(buf^1, k+32) FIRST, then ds_read+MFMA
// on buf[cur], then ONE vmcnt(0)+s_barrier. The prefetch stays in flight
// under the whole compute phase (vs m97's drain-before-compute), which is
// what a 2-blocks/CU grid needs. Output: fp32 partials [z][M][N].
// ---------------------------------------------------------------------------
__global__ __launch_bounds__(256) void gemm_db(
    const bf16* __restrict__ A, const bf16* __restrict__ B,
    float* __restrict__ Cp, int N, int Kd, int lda, int ldb)
{
    __shared__ bf16 As[2][128 * 32];
    __shared__ bf16 Bs[2][128 * 32];

    const int tid  = threadIdx.x;
    const int wave = tid >> 6, lane = tid & 63;
    const int quad = lane >> 4, l16 = lane & 15;
    const int wm = (wave & 1) * 64, wn = (wave >> 1) * 64;
    const long baseM = (long)blockIdx.x * 128;
    const long baseN = (long)blockIdx.y * 128;
    const long koff  = (long)blockIdx.z * Kd;

    const int  srow = wave * 16 + (lane >> 2);
    const int  scol = (lane & 3) * 8;
    const long aoff0 = (baseM + srow) * (long)lda + koff + scol;
    const long aoff1 = (baseM + 64 + srow) * (long)lda + koff + scol;
    const long boff0 = (baseN + srow) * (long)ldb + koff + scol;
    const long boff1 = (baseN + 64 + srow) * (long)ldb + koff + scol;
    const int  lds0 = wave * 512;
    const int  lds1 = 2048 + wave * 512;

    auto stage = [&](int p, int k0) {
        __builtin_amdgcn_global_load_lds(GLOBAL_AS(A + aoff0 + k0), LDS_AS(As[p] + lds0), 16, 0, 0);
        __builtin_amdgcn_global_load_lds(GLOBAL_AS(A + aoff1 + k0), LDS_AS(As[p] + lds1), 16, 0, 0);
        __builtin_amdgcn_global_load_lds(GLOBAL_AS(B + boff0 + k0), LDS_AS(Bs[p] + lds0), 16, 0, 0);
        __builtin_amdgcn_global_load_lds(GLOBAL_AS(B + boff1 + k0), LDS_AS(Bs[p] + lds1), 16, 0, 0);
    };

    floatx4 acc[4][4] = {};

    stage(0, 0);
    asm volatile("s_waitcnt vmcnt(0)" ::: "memory");
    __builtin_amdgcn_s_barrier();

    int cur = 0;
    for (int k0 = 0; k0 < Kd; k0 += 32) {
        if (k0 + 32 < Kd) stage(cur ^ 1, k0 + 32);   // prefetch next tile
        __builtin_amdgcn_sched_barrier(0);           // pin load issue before compute

        bf16x8 af[4], bfr[4];
        #pragma unroll
        for (int i = 0; i < 4; ++i)
            af[i] = *(const bf16x8*)(As[cur] + (wm + i * 16 + l16) * 32 + quad * 8);
        #pragma unroll
        for (int j = 0; j < 4; ++j)
            bfr[j] = *(const bf16x8*)(Bs[cur] + (wn + j * 16 + l16) * 32 + quad * 8);

        #pragma unroll
        for (int i = 0; i < 4; ++i)
            #pragma unroll
            for (int j = 0; j < 4; ++j)
                acc[i][j] = __builtin_amdgcn_mfma_f32_16x16x32_bf16(af[i], bfr[j], acc[i][j], 0, 0, 0);

        asm volatile("s_waitcnt vmcnt(0)" ::: "memory");  // next tile landed
        __builtin_amdgcn_s_barrier();                     // all readers of cur done
        cur ^= 1;
    }

    const long Mrows = (long)gridDim.x * 128;
    float* C = Cp + (long)blockIdx.z * Mrows * N;
    #pragma unroll
    for (int i = 0; i < 4; ++i)
        #pragma unroll
        for (int j = 0; j < 4; ++j)
            #pragma unroll
            for (int r = 0; r < 4; ++r) {
                long row = baseM + wm + i * 16 + quad * 4 + r;
                long col = baseN + wn + j * 16 + l16;
                C[row * (long)N + col] = acc[i][j][r];
            }
}

// ---------------------------------------------------------------------------
// reduce2: out = P0 + P1, cast per flag. 32MB read + 8/16MB write, HBM-bound.
// ---------------------------------------------------------------------------
__global__ __launch_bounds__(256) void reduce2(
    const float* __restrict__ P0, const float* __restrict__ P1,
    void* __restrict__ out, const int* flagp)
{
    long i = ((long)blockIdx.x * 256 + threadIdx.x) * 4;
    floatx4 a = *(const floatx4*)(P0 + i);
    floatx4 b = *(const floatx4*)(P1 + i);
    floatx4 s = a + b;
    if (*flagp) {
        bf16x4 o;
        #pragma unroll
        for (int r = 0; r < 4; ++r) o[r] = (bf16)s[r];
        *(bf16x4*)((bf16*)out + i) = o;
    } else {
        *(floatx4*)((float*)out + i) = s;
    }
}

// ---------------------------------------------------------------------------
// In-place RMSNorm + RoPE on q/k sections of qkv[t][6144].
// ---------------------------------------------------------------------------
__global__ __launch_bounds__(256) void qkv_post(
    bf16* __restrict__ qkv, const int* __restrict__ positions,
    const bf16* __restrict__ qnw, const bf16* __restrict__ knw)
{
    const int t = blockIdx.x;
    const int tid = threadIdx.x, wave = tid >> 6, lane = tid & 63;
    const float pos = (float)positions[t];

    const float inv = expf(-(float)lane * (float)(9.210340371976184 / 64.0));
    float sn, cs;
    sincosf(pos * inv, &sn, &cs);

    bf16* row = qkv + (long)t * QKV_N;

    for (int u = wave; u < 40; u += 4) {
        bf16* p       = (u < 32) ? row + u * HD : row + Q_SIZE + (u - 32) * HD;
        const bf16* w = (u < 32) ? qnw : knw;
        float x1 = (float)p[lane], x2 = (float)p[lane + 64];
        float ss = x1 * x1 + x2 * x2;
        #pragma unroll
        for (int m = 32; m; m >>= 1) ss += __shfl_xor(ss, m);
        float rr = rsqrtf(ss * (1.f / 128.f) + 1e-6f);
        float y1 = x1 * rr * (float)w[lane];
        float y2 = x2 * rr * (float)w[lane + 64];
        p[lane]      = (bf16)(y1 * cs - y2 * sn);
        p[lane + 64] = (bf16)(y2 * cs + y1 * sn);
    }
}

// ---------------------------------------------------------------------------
// V transpose: vt[kvh][d][t] from qkv[t][5120+kvh*128+d].
// ---------------------------------------------------------------------------
__global__ __launch_bounds__(256) void vtrans(const bf16* __restrict__ qkv,
                                              bf16* __restrict__ vt)
{
    __shared__ bf16 tile[64][136];
    const int t0 = blockIdx.x * 64, kvh = blockIdx.y, tid = threadIdx.x;

    const int rl = tid >> 4, c8 = (tid & 15) * 8;
    const bf16* src = qkv + (long)t0 * QKV_N + 5120 + kvh * HD;
    #pragma unroll
    for (int it = 0; it < 4; ++it) {
        int r = it * 16 + rl;
        *(bf16x8*)(&tile[r][c8]) = *(const bf16x8*)(src + (long)r * QKV_N + c8);
    }
    __syncthreads();

    const int d = tid >> 1, tb = (tid & 1) * 32;
    bf16* dst = vt + ((long)kvh * HD + d) * T_SEQ + t0 + tb;
    #pragma unroll
    for (int it = 0; it < 4; ++it) {
        bf16x8 v;
        #pragma unroll
        for (int j = 0; j < 8; ++j) v[j] = tile[tb + it * 8 + j][d];
        *(bf16x8*)(dst + it * 8) = v;
    }
}

// ---------------------------------------------------------------------------
// attn5: unpaired 64-row q-tiles, grid (head, 32) with iq = 31 - blockIdx.y
// (LPT: longest tiles dispatch first). 1024 blocks; LDS = 48KB (K dbuf +
// single V) -> 3 blocks/CU = 12 waves/CU. Two barriers/iter; counted
// vmcnt(4) mid-iter keeps the K[t+1] prefetch in flight. P fully in-register
// via sigma'd K staging + v_cvt_pk_bf16_f32 + permlane32_swap.
// ---------------------------------------------------------------------------
__global__ __launch_bounds__(256, 3) void attn5(bf16* qkv, const bf16* __restrict__ vt)
{
    __shared__ bf16 Ks[2][64 * 128];   // [kt-row][d], 16B chunk c at c^(row&15), rows sigma'd
    __shared__ bf16 Vs[128 * 64];      // [d][kt-row], 16B chunk c at c^(d&7), single buffer

    const int tid  = threadIdx.x, wave = tid >> 6, lane = tid & 63;
    const int quad = lane >> 4, l16 = lane & 15;
    const int h = blockIdx.x, kvh = h >> 2;
    const int iq = 31 - blockIdx.y;    // tile index, longest first (LPT)
    const int q0 = iq * 64;

    const float C1 = 0.12753236f;      // 128^-0.5 * log2(e)
    const float C2 = 17.312340f;       // 12 * log2(e)

    // Q fragments (MFMA B-operand)
    bf16x8 qf[4];
    {
        const bf16* qa = qkv + (long)(q0 + wave * 16 + l16) * QKV_N + h * HD + quad * 8;
        #pragma unroll
        for (int ks = 0; ks < 4; ++ks) qf[ks] = *(const bf16x8*)(qa + ks * 32);
    }

    floatx4 oacc[8] = {};
    float ls = 0.f;                    // per-lane partial row sum

    const int krl = lane >> 4, kc = lane & 15;
    const int vrl = lane >> 3, vc = lane & 7;
    const int kswz = (kc ^ (wave * 4 + krl)) * 8;
    const int vswz = (vc ^ (vrl & 7)) * 8;
    const int wsig = ((wave & 1) << 1) | (wave >> 1);           // sigma(wave): 1<->2
    const int sq4  = (((quad & 1) << 1) | (quad >> 1)) << 2;    // sigma(quad)*4

    const bf16* kg0 = qkv + Q_SIZE + kvh * HD;
    const bf16* vg0 = vt + (long)kvh * HD * T_SEQ;

    // K stage: LDS slot row (it*16 + wave*4 + krl) gets GLOBAL row
    // (it*16 + sigma(wave)*4 + krl); chunk swizzle stays slot-row-based.
    auto stageK = [&](int p, int kt) {
        const bf16* kg = kg0 + (long)(kt * 64) * QKV_N;
        #pragma unroll
        for (int it = 0; it < 4; ++it) {
            const int rK = it * 16 + wsig * 4 + krl;
            __builtin_amdgcn_global_load_lds(GLOBAL_AS(kg + (long)rK * QKV_N + kswz),
                                             LDS_AS(&Ks[p][it * 2048 + wave * 512]), 16, 0, 0);
        }
    };
    auto stageV = [&](int kt) {
        const bf16* vg = vg0 + kt * 64;
        #pragma unroll
        for (int it = 0; it < 4; ++it) {
            const int dV = it * 32 + wave * 8 + vrl;
            __builtin_amdgcn_global_load_lds(GLOBAL_AS(vg + (long)dV * T_SEQ + vswz),
                                             LDS_AS(&Vs[it * 2048 + wave * 512]), 16, 0, 0);
        }
    };

    stageK(0, 0);

    const int qg = q0 + wave * 16 + l16;

    for (int kt = 0; kt <= iq; ++kt) {
        const int p = kt & 1;
        __syncthreads();                   // K[p] landed (vmcnt0); all Vs readers done
        stageV(kt);                        // V first (counted-wait relies on FIFO retire)
        if (kt < iq) stageK(p ^ 1, kt + 1);

        const int k0 = kt * 64;

        // S^T = K Q^T (rows = sigma'd kt, cols = q)
        floatx4 sT[4] = {};
        #pragma unroll
        for (int j2 = 0; j2 < 4; ++j2)
            #pragma unroll
            for (int ks = 0; ks < 4; ++ks) {
                bf16x8 kf = *(const bf16x8*)(&Ks[p][(j2 * 16 + l16) * 128 + (((ks * 4 + quad) ^ l16) * 8)]);
                sT[j2] = __builtin_amdgcn_mfma_f32_16x16x32_bf16(kf, qf[ks], sT[j2], 0, 0, 0);
            }

        // softmax numerators, fully in-register: this lane's element (j2,r)
        // is P(q = l16, kt = k0 + j2*16 + sigma(quad)*4 + r)
        const bool diag = (kt == iq);
        unsigned lov[4], hiv[4];
        #pragma unroll
        for (int j2 = 0; j2 < 4; ++j2) {
            float ev[4];
            #pragma unroll
            for (int r = 0; r < 4; ++r) {
                float x = __builtin_amdgcn_exp2f(sT[j2][r] * C1 - C2);
                if (diag && (k0 + j2 * 16 + sq4 + r > qg)) x = 0.f;
                ls += x;
                ev[r] = x;
            }
            asm("v_cvt_pk_bf16_f32 %0, %1, %2" : "=v"(lov[j2]) : "v"(ev[0]), "v"(ev[1]));
            asm("v_cvt_pk_bf16_f32 %0, %1, %2" : "=v"(hiv[j2]) : "v"(ev[2]), "v"(ev[3]));
        }

        // lane+-32 redistribution to PV A-operand layout:
        // pa[ks2] elem j = P(l16, ks2*32 + quad*8 + j)
        bf16x8 pa[2];
        #pragma unroll
        for (int ks2 = 0; ks2 < 2; ++ks2) {
            auto wl = __builtin_amdgcn_permlane32_swap(lov[2 * ks2], lov[2 * ks2 + 1], false, false);
            auto wh = __builtin_amdgcn_permlane32_swap(hiv[2 * ks2], hiv[2 * ks2 + 1], false, false);
            union { unsigned w[4]; bf16x8 v; } u;
            u.w[0] = wl[0]; u.w[1] = wh[0]; u.w[2] = wl[1]; u.w[3] = wh[1];
            pa[ks2] = u.v;
        }

        // mid barrier: V[kt] landed (4 oldest loads retired), K[t+1] stays in flight
        if (kt < iq) asm volatile("s_waitcnt vmcnt(4)" ::: "memory");
        else         asm volatile("s_waitcnt vmcnt(0)" ::: "memory");
        __builtin_amdgcn_s_barrier();
        __builtin_amdgcn_sched_barrier(0);

        // O += P V
        #pragma unroll
        for (int ks2 = 0; ks2 < 2; ++ks2)
            #pragma unroll
            for (int vj = 0; vj < 8; ++vj) {
                const int d = vj * 16 + l16;
                bf16x8 vb = *(const bf16x8*)(&Vs[d * 64 + (((ks2 * 4 + quad) ^ (d & 7)) * 8)]);
                oacc[vj] = __builtin_amdgcn_mfma_f32_16x16x32_bf16(pa[ks2], vb, oacc[vj], 0, 0, 0);
            }
    }

    // total row sums: reduce over quads (lane l16 holds q-row l16's sum)
    ls += __shfl_xor(ls, 16); ls += __shfl_xor(ls, 32);
    float rinv[4];
    #pragma unroll
    for (int r = 0; r < 4; ++r) rinv[r] = 1.f / __shfl(ls, quad * 4 + r);

    #pragma unroll
    for (int vj = 0; vj < 8; ++vj)
        #pragma unroll
        for (int r = 0; r < 4; ++r) {
            const long row = q0 + wave * 16 + quad * 4 + r;
            qkv[row * (long)QKV_N + h * HD + vj * 16 + l16] = (bf16)(oacc[vj][r] * rinv[r]);
        }
}

// ---------------------------------------------------------------------------
extern "C" void kernel_launch(void* const* d_in, const int* in_sizes, int n_in,
                              void* d_out, int out_size, void* d_ws, size_t ws_size,
                              hipStream_t stream)
{
    const int* positions = (const int*)d_in[0];

    char* ws = (char*)d_ws;
    bf16* qkv  = (bf16*)(ws);              // [2048][6144]  25165824 B
    bf16* hb   = (bf16*)(ws + 25165824);   // [2048][2048]   8388608 B (dead after gemm1)
    bf16* vt   = hb;                       // [8][128][2048] 4194304 B (aliases hb)
    // o-proj split-K partials: live only after attn5 (hb/vt and wqb both dead)
    float* P0  = (float*)(ws + 25165824);  // [2048][2048] fp32 16777216 B
    float* P1  = (float*)(ws + 41943040);  // [2048][2048] fp32 16777216 B (ends at wob)
    bf16* wqb  = (bf16*)(ws + 33554432);   // [6144][2048]  25165824 B
    bf16* wob  = (bf16*)(ws + 58720256);   // [2048][4096]  16777216 B
    bf16* qnb  = (bf16*)(ws + 75497472);
    bf16* knb  = (bf16*)(ws + 75497728);
    int*  flag = (int*) (ws + 75497984);

    detect_dtype<<<dim3(1), dim3(64), 0, stream>>>((const unsigned short*)d_in[2], flag);
    convert_all<<<dim3(12289), dim3(256), 0, stream>>>(
        d_in[1], d_in[2], d_in[3], d_in[4], d_in[5],
        hb, wqb, wob, qnb, knb, flag);

    dim3 blk(256);
    gemm_bt<<<dim3(T_SEQ / 128, QKV_N / 128), blk, 0, stream>>>(
        hb, wqb, qkv, T_SEQ, QKV_N, HIDDEN, HIDDEN, flag, 0);
    vtrans<<<dim3(T_SEQ / 64, NUM_KV), blk, 0, stream>>>(qkv, vt);
    qkv_post<<<dim3(T_SEQ), blk, 0, stream>>>(qkv, positions, qnb, knb);
    attn5<<<dim3(NUM_H, 32), blk, 0, stream>>>(qkv, vt);
    // o-proj: C[2048,2048] = attn_out[2048,4096(@lda 6144)] * wo[2048,4096]^T
    // split-K=2 (z), 128x128 dbuf tiles, fp32 partials, then reduce.
    gemm_db<<<dim3(T_SEQ / 128, HIDDEN / 128, 2), blk, 0, stream>>>(
        qkv, wob, P0, HIDDEN, Q_SIZE / 2, QKV_N, Q_SIZE);
    reduce2<<<dim3(4096), blk, 0, stream>>>(P0, P1, d_out, flag);
}

// Round 3
// 329.606 us; speedup vs baseline: 1.2005x; 1.0386x over previous
//
#include <hip/hip_runtime.h>
#include <hip/hip_bf16.h>

#define T_SEQ   2048
#define HIDDEN  2048
#define NUM_H   32
#define NUM_KV  8
#define HD      128
#define Q_SIZE  4096
#define QKV_N   6144

typedef __bf16 bf16;
typedef __bf16 bf16x8 __attribute__((ext_vector_type(8)));
typedef __bf16 bf16x4 __attribute__((ext_vector_type(4)));
typedef float  floatx4 __attribute__((ext_vector_type(4)));

#define GLOBAL_AS(p) ((const __attribute__((address_space(1))) void*)(p))
#define LDS_AS(p)    ((__attribute__((address_space(3))) void*)(p))

// memory-clobber-wrapped barrier: blocks compiler memory reordering across it
#define BARRIER() do { asm volatile("" ::: "memory"); \
                       __builtin_amdgcn_s_barrier();  \
                       asm volatile("" ::: "memory"); } while (0)

// ---------------------------------------------------------------------------
// Dtype detection (fp32 vs bf16 inputs). flag=1 => bf16.
// ---------------------------------------------------------------------------
__global__ void detect_dtype(const unsigned short* __restrict__ wq, int* flagp)
{
    const int lane = threadIdx.x;   // 64 threads
    int cnt = 0;
    for (int i = lane; i < 512; i += 64) {
        int ef = (wq[i] >> 7) & 0xFF;
        if (ef >= 90 && ef <= 130) cnt++;
    }
    #pragma unroll
    for (int m = 32; m; m >>= 1) cnt += __shfl_xor(cnt, m);
    if (lane == 0) *flagp = (cnt >= 430) ? 1 : 0;
}

// ---------------------------------------------------------------------------
// Canonicalize all float inputs into bf16 workspace copies.
// ---------------------------------------------------------------------------
__global__ __launch_bounds__(256) void convert_all(
    const void* __restrict__ h, const void* __restrict__ wq,
    const void* __restrict__ wo_, const void* __restrict__ qn,
    const void* __restrict__ kn,
    bf16* __restrict__ hb, bf16* __restrict__ wqb, bf16* __restrict__ wob,
    bf16* __restrict__ qnb, bf16* __restrict__ knb, const int* flagp)
{
    long e = ((long)blockIdx.x * 256 + threadIdx.x) * 8;
    const void* src; bf16* dst; long off;
    if      (e < 4194304)  { src = h;   dst = hb;  off = e; }
    else if (e < 16777216) { src = wq;  dst = wqb; off = e - 4194304; }
    else if (e < 25165824) { src = wo_; dst = wob; off = e - 16777216; }
    else if (e < 25165952) { src = qn;  dst = qnb; off = e - 25165824; }
    else if (e < 25166080) { src = kn;  dst = knb; off = e - 25165952; }
    else return;

    if (*flagp) {
        *(bf16x8*)(dst + off) = *(const bf16x8*)((const bf16*)src + off);
    } else {
        const float* f = (const float*)src + off;
        bf16x8 v;
        #pragma unroll
        for (int i = 0; i < 8; ++i) v[i] = (bf16)f[i];
        *(bf16x8*)(dst + off) = v;
    }
}

// ---------------------------------------------------------------------------
// gemm8p: NT GEMM, 256x256 tile, BK=64, 8 waves (2M x 4N), 512 threads,
// 128 KB LDS (A,B x 2 halves x dbuf). T3+T4 structure: stage next K-tile's
// 8 global_load_lds at iteration top, counted vmcnt(8) (prefetch never
// drained), one barrier, then 4 quadrant clusters {ds_read subtile ->
// 16 MFMA (setprio-wrapped)}, one trailing barrier. LDS bank conflicts
// killed by 16B-chunk XOR swizzle (chunk c at c^(row&7)), applied on the
// pre-swizzled GLOBAL source (linear LDS dest, rule #21) and re-applied on
// the ds_read address. bf16 output. Grid (M/256, N/256), x-fastest dispatch
// puts one A-panel per XCD (L2-resident) across all N-tiles.
// ---------------------------------------------------------------------------
__global__ __launch_bounds__(512, 2) void gemm8p(
    const bf16* __restrict__ A, const bf16* __restrict__ B,
    bf16* __restrict__ C, int N, int K, int lda, int ldb)
{
    __shared__ bf16 As[2][2][128 * 64];   // [dbuf][half][row*64 + col]
    __shared__ bf16 Bs[2][2][128 * 64];

    const int tid  = threadIdx.x;
    const int wave = tid >> 6, lane = tid & 63;
    const int quad = lane >> 4, l16 = lane & 15;
    const int wm = wave >> 2;            // 0..1 : M half (= A half this wave reads)
    const int wn = wave & 3;             // 0..3 : N quarter
    const int wh = wn >> 1;              // B half this wave reads
    const int bro = (wn & 1) * 64;       // row offset within B half
    const long baseM = (long)blockIdx.x * 256;
    const long baseN = (long)blockIdx.y * 256;

    // staging geometry: load l in 0..7 -> half-tile (A h0, A h1, B h0, B h1) x2
    // chunk n = (l&1)*512 + tid; row = n>>3, slot = n&7, global chunk = slot^(row&7)
    auto stage = [&](int p, int t) {
        const long kc = (long)t * 64;
        #pragma unroll
        for (int l = 0; l < 8; ++l) {
            const int h   = (l >> 1) & 1;
            const int n0  = (l & 1) * 512 + wave * 64;
            const int n   = n0 + lane;
            const int row = n >> 3, slot = n & 7;
            const int gc  = (slot ^ (row & 7)) * 8;
            if (l < 4)
                __builtin_amdgcn_global_load_lds(
                    GLOBAL_AS(A + (baseM + h * 128 + row) * (long)lda + kc + gc),
                    LDS_AS(&As[p][h][n0 * 8]), 16, 0, 0);
            else
                __builtin_amdgcn_global_load_lds(
                    GLOBAL_AS(B + (baseN + h * 128 + row) * (long)ldb + kc + gc),
                    LDS_AS(&Bs[p][h][n0 * 8]), 16, 0, 0);
        }
    };

    floatx4 acc[8][4] = {};   // [mf 0..7][nf 0..3], 128 f32

    stage(0, 0);

    const int NT = K / 64;
    for (int t = 0; t < NT; ++t) {
        const int p = t & 1;
        if (t + 1 < NT) {
            stage(p ^ 1, t + 1);                              // prefetch next tile
            asm volatile("s_waitcnt vmcnt(8)" ::: "memory");  // tile t landed, t+1 in flight
        } else {
            asm volatile("s_waitcnt vmcnt(0)" ::: "memory");
        }
        __builtin_amdgcn_sched_barrier(0);
        BARRIER();                                            // tile t visible to all waves

        const bf16* Aw = &As[p][wm][0];
        const bf16* Bw = &Bs[p][wh][0];

        bf16x8 af[4][2], bf0[2][2], bf1[2][2];

        // ---- quadrant (0,0): A rows 0..63 of wave, B cols 0..31 of wave ----
        #pragma unroll
        for (int mf = 0; mf < 4; ++mf)
            #pragma unroll
            for (int ks = 0; ks < 2; ++ks) {
                const int r = mf * 16 + l16;
                af[mf][ks] = *(const bf16x8*)(Aw + r * 64 + (((ks * 4 + quad) ^ (r & 7)) * 8));
            }
        #pragma unroll
        for (int nf = 0; nf < 2; ++nf)
            #pragma unroll
            for (int ks = 0; ks < 2; ++ks) {
                const int r = bro + nf * 16 + l16;
                bf0[nf][ks] = *(const bf16x8*)(Bw + r * 64 + (((ks * 4 + quad) ^ (r & 7)) * 8));
            }
        __builtin_amdgcn_s_setprio(1);
        #pragma unroll
        for (int mf = 0; mf < 4; ++mf)
            #pragma unroll
            for (int nf = 0; nf < 2; ++nf)
                #pragma unroll
                for (int ks = 0; ks < 2; ++ks)
                    acc[mf][nf] = __builtin_amdgcn_mfma_f32_16x16x32_bf16(af[mf][ks], bf0[nf][ks], acc[mf][nf], 0, 0, 0);
        __builtin_amdgcn_s_setprio(0);

        // ---- quadrant (0,1): B cols 32..63 ----
        #pragma unroll
        for (int nf = 0; nf < 2; ++nf)
            #pragma unroll
            for (int ks = 0; ks < 2; ++ks) {
                const int r = bro + (nf + 2) * 16 + l16;
                bf1[nf][ks] = *(const bf16x8*)(Bw + r * 64 + (((ks * 4 + quad) ^ (r & 7)) * 8));
            }
        __builtin_amdgcn_s_setprio(1);
        #pragma unroll
        for (int mf = 0; mf < 4; ++mf)
            #pragma unroll
            for (int nf = 0; nf < 2; ++nf)
                #pragma unroll
                for (int ks = 0; ks < 2; ++ks)
                    acc[mf][nf + 2] = __builtin_amdgcn_mfma_f32_16x16x32_bf16(af[mf][ks], bf1[nf][ks], acc[mf][nf + 2], 0, 0, 0);
        __builtin_amdgcn_s_setprio(0);

        // ---- quadrant (1,0): A rows 64..127 (reuse af regs), B cols 0..31 ----
        #pragma unroll
        for (int mf = 0; mf < 4; ++mf)
            #pragma unroll
            for (int ks = 0; ks < 2; ++ks) {
                const int r = (mf + 4) * 16 + l16;
                af[mf][ks] = *(const bf16x8*)(Aw + r * 64 + (((ks * 4 + quad) ^ (r & 7)) * 8));
            }
        __builtin_amdgcn_s_setprio(1);
        #pragma unroll
        for (int mf = 0; mf < 4; ++mf)
            #pragma unroll
            for (int nf = 0; nf < 2; ++nf)
                #pragma unroll
                for (int ks = 0; ks < 2; ++ks)
                    acc[mf + 4][nf] = __builtin_amdgcn_mfma_f32_16x16x32_bf16(af[mf][ks], bf0[nf][ks], acc[mf + 4][nf], 0, 0, 0);
        __builtin_amdgcn_s_setprio(0);

        // ---- quadrant (1,1) ----
        __builtin_amdgcn_s_setprio(1);
        #pragma unroll
        for (int mf = 0; mf < 4; ++mf)
            #pragma unroll
            for (int nf = 0; nf < 2; ++nf)
                #pragma unroll
                for (int ks = 0; ks < 2; ++ks)
                    acc[mf + 4][nf + 2] = __builtin_amdgcn_mfma_f32_16x16x32_bf16(af[mf][ks], bf1[nf][ks], acc[mf + 4][nf + 2], 0, 0, 0);
        __builtin_amdgcn_s_setprio(0);

        BARRIER();   // all waves done reading buf p -> next stage may overwrite p^1
    }

    #pragma unroll
    for (int i = 0; i < 8; ++i)
        #pragma unroll
        for (int j = 0; j < 4; ++j)
            #pragma unroll
            for (int r = 0; r < 4; ++r) {
                long row = baseM + wm * 128 + i * 16 + quad * 4 + r;
                long col = baseN + wn * 64 + j * 16 + l16;
                C[row * (long)N + col] = (bf16)acc[i][j][r];
            }
}

// ---------------------------------------------------------------------------
// gemm_db: NT GEMM 128x128, double-buffered 2-phase, split-K via blockIdx.z.
// fp32 partials [z][M][N]. (o-proj; proven last round.)
// ---------------------------------------------------------------------------
__global__ __launch_bounds__(256) void gemm_db(
    const bf16* __restrict__ A, const bf16* __restrict__ B,
    float* __restrict__ Cp, int N, int Kd, int lda, int ldb)
{
    __shared__ bf16 As[2][128 * 32];
    __shared__ bf16 Bs[2][128 * 32];

    const int tid  = threadIdx.x;
    const int wave = tid >> 6, lane = tid & 63;
    const int quad = lane >> 4, l16 = lane & 15;
    const int wm = (wave & 1) * 64, wn = (wave >> 1) * 64;
    const long baseM = (long)blockIdx.x * 128;
    const long baseN = (long)blockIdx.y * 128;
    const long koff  = (long)blockIdx.z * Kd;

    const int  srow = wave * 16 + (lane >> 2);
    const int  scol = (lane & 3) * 8;
    const long aoff0 = (baseM + srow) * (long)lda + koff + scol;
    const long aoff1 = (baseM + 64 + srow) * (long)lda + koff + scol;
    const long boff0 = (baseN + srow) * (long)ldb + koff + scol;
    const long boff1 = (baseN + 64 + srow) * (long)ldb + koff + scol;
    const int  lds0 = wave * 512;
    const int  lds1 = 2048 + wave * 512;

    auto stage = [&](int p, int k0) {
        __builtin_amdgcn_global_load_lds(GLOBAL_AS(A + aoff0 + k0), LDS_AS(As[p] + lds0), 16, 0, 0);
        __builtin_amdgcn_global_load_lds(GLOBAL_AS(A + aoff1 + k0), LDS_AS(As[p] + lds1), 16, 0, 0);
        __builtin_amdgcn_global_load_lds(GLOBAL_AS(B + boff0 + k0), LDS_AS(Bs[p] + lds0), 16, 0, 0);
        __builtin_amdgcn_global_load_lds(GLOBAL_AS(B + boff1 + k0), LDS_AS(Bs[p] + lds1), 16, 0, 0);
    };

    floatx4 acc[4][4] = {};

    stage(0, 0);
    asm volatile("s_waitcnt vmcnt(0)" ::: "memory");
    __builtin_amdgcn_s_barrier();

    int cur = 0;
    for (int k0 = 0; k0 < Kd; k0 += 32) {
        if (k0 + 32 < Kd) stage(cur ^ 1, k0 + 32);   // prefetch next tile
        __builtin_amdgcn_sched_barrier(0);           // pin load issue before compute

        bf16x8 af[4], bfr[4];
        #pragma unroll
        for (int i = 0; i < 4; ++i)
            af[i] = *(const bf16x8*)(As[cur] + (wm + i * 16 + l16) * 32 + quad * 8);
        #pragma unroll
        for (int j = 0; j < 4; ++j)
            bfr[j] = *(const bf16x8*)(Bs[cur] + (wn + j * 16 + l16) * 32 + quad * 8);

        #pragma unroll
        for (int i = 0; i < 4; ++i)
            #pragma unroll
            for (int j = 0; j < 4; ++j)
                acc[i][j] = __builtin_amdgcn_mfma_f32_16x16x32_bf16(af[i], bfr[j], acc[i][j], 0, 0, 0);

        asm volatile("s_waitcnt vmcnt(0)" ::: "memory");  // next tile landed
        __builtin_amdgcn_s_barrier();                     // all readers of cur done
        cur ^= 1;
    }

    const long Mrows = (long)gridDim.x * 128;
    float* C = Cp + (long)blockIdx.z * Mrows * N;
    #pragma unroll
    for (int i = 0; i < 4; ++i)
        #pragma unroll
        for (int j = 0; j < 4; ++j)
            #pragma unroll
            for (int r = 0; r < 4; ++r) {
                long row = baseM + wm + i * 16 + quad * 4 + r;
                long col = baseN + wn + j * 16 + l16;
                C[row * (long)N + col] = acc[i][j][r];
            }
}

// ---------------------------------------------------------------------------
// reduce2: out = P0 + P1, cast per flag. HBM-bound.
// ---------------------------------------------------------------------------
__global__ __launch_bounds__(256) void reduce2(
    const float* __restrict__ P0, const float* __restrict__ P1,
    void* __restrict__ out, const int* flagp)
{
    long i = ((long)blockIdx.x * 256 + threadIdx.x) * 4;
    floatx4 a = *(const floatx4*)(P0 + i);
    floatx4 b = *(const floatx4*)(P1 + i);
    floatx4 s = a + b;
    if (*flagp) {
        bf16x4 o;
        #pragma unroll
        for (int r = 0; r < 4; ++r) o[r] = (bf16)s[r];
        *(bf16x4*)((bf16*)out + i) = o;
    } else {
        *(floatx4*)((float*)out + i) = s;
    }
}

// ---------------------------------------------------------------------------
// In-place RMSNorm + RoPE on q/k sections of qkv[t][6144].
// ---------------------------------------------------------------------------
__global__ __launch_bounds__(256) void qkv_post(
    bf16* __restrict__ qkv, const int* __restrict__ positions,
    const bf16* __restrict__ qnw, const bf16* __restrict__ knw)
{
    const int t = blockIdx.x;
    const int tid = threadIdx.x, wave = tid >> 6, lane = tid & 63;
    const float pos = (float)positions[t];

    const float inv = expf(-(float)lane * (float)(9.210340371976184 / 64.0));
    float sn, cs;
    sincosf(pos * inv, &sn, &cs);

    bf16* row = qkv + (long)t * QKV_N;

    for (int u = wave; u < 40; u += 4) {
        bf16* p       = (u < 32) ? row + u * HD : row + Q_SIZE + (u - 32) * HD;
        const bf16* w = (u < 32) ? qnw : knw;
        float x1 = (float)p[lane], x2 = (float)p[lane + 64];
        float ss = x1 * x1 + x2 * x2;
        #pragma unroll
        for (int m = 32; m; m >>= 1) ss += __shfl_xor(ss, m);
        float rr = rsqrtf(ss * (1.f / 128.f) + 1e-6f);
        float y1 = x1 * rr * (float)w[lane];
        float y2 = x2 * rr * (float)w[lane + 64];
        p[lane]      = (bf16)(y1 * cs - y2 * sn);
        p[lane + 64] = (bf16)(y2 * cs + y1 * sn);
    }
}

// ---------------------------------------------------------------------------
// V transpose: vt[kvh][d][t] from qkv[t][5120+kvh*128+d].
// ---------------------------------------------------------------------------
__global__ __launch_bounds__(256) void vtrans(const bf16* __restrict__ qkv,
                                              bf16* __restrict__ vt)
{
    __shared__ bf16 tile[64][136];
    const int t0 = blockIdx.x * 64, kvh = blockIdx.y, tid = threadIdx.x;

    const int rl = tid >> 4, c8 = (tid & 15) * 8;
    const bf16* src = qkv + (long)t0 * QKV_N + 5120 + kvh * HD;
    #pragma unroll
    for (int it = 0; it < 4; ++it) {
        int r = it * 16 + rl;
        *(bf16x8*)(&tile[r][c8]) = *(const bf16x8*)(src + (long)r * QKV_N + c8);
    }
    __syncthreads();

    const int d = tid >> 1, tb = (tid & 1) * 32;
    bf16* dst = vt + ((long)kvh * HD + d) * T_SEQ + t0 + tb;
    #pragma unroll
    for (int it = 0; it < 4; ++it) {
        bf16x8 v;
        #pragma unroll
        for (int j = 0; j < 8; ++j) v[j] = tile[tb + it * 8 + j][d];
        *(bf16x8*)(dst + it * 8) = v;
    }
}

// ---------------------------------------------------------------------------
// attn5: unpaired 64-row q-tiles, grid (head, 32) with iq = 31 - blockIdx.y
// (LPT). 1024 blocks; LDS 48KB -> 3 blocks/CU. Counted vmcnt(4) mid-iter
// keeps the K[t+1] prefetch in flight. P fully in-register via sigma'd K
// staging + v_cvt_pk_bf16_f32 + permlane32_swap.
// ---------------------------------------------------------------------------
__global__ __launch_bounds__(256, 3) void attn5(bf16* qkv, const bf16* __restrict__ vt)
{
    __shared__ bf16 Ks[2][64 * 128];   // [kt-row][d], 16B chunk c at c^(row&15), rows sigma'd
    __shared__ bf16 Vs[128 * 64];      // [d][kt-row], 16B chunk c at c^(d&7), single buffer

    const int tid  = threadIdx.x, wave = tid >> 6, lane = tid & 63;
    const int quad = lane >> 4, l16 = lane & 15;
    const int h = blockIdx.x, kvh = h >> 2;
    const int iq = 31 - blockIdx.y;    // tile index, longest first (LPT)
    const int q0 = iq * 64;

    const float C1 = 0.12753236f;      // 128^-0.5 * log2(e)
    const float C2 = 17.312340f;       // 12 * log2(e)

    // Q fragments (MFMA B-operand)
    bf16x8 qf[4];
    {
        const bf16* qa = qkv + (long)(q0 + wave * 16 + l16) * QKV_N + h * HD + quad * 8;
        #pragma unroll
        for (int ks = 0; ks < 4; ++ks) qf[ks] = *(const bf16x8*)(qa + ks * 32);
    }

    floatx4 oacc[8] = {};
    float ls = 0.f;                    // per-lane partial row sum

    const int krl = lane >> 4, kc = lane & 15;
    const int vrl = lane >> 3, vc = lane & 7;
    const int kswz = (kc ^ (wave * 4 + krl)) * 8;
    const int vswz = (vc ^ (vrl & 7)) * 8;
    const int wsig = ((wave & 1) << 1) | (wave >> 1);           // sigma(wave): 1<->2
    const int sq4  = (((quad & 1) << 1) | (quad >> 1)) << 2;    // sigma(quad)*4

    const bf16* kg0 = qkv + Q_SIZE + kvh * HD;
    const bf16* vg0 = vt + (long)kvh * HD * T_SEQ;

    auto stageK = [&](int p, int kt) {
        const bf16* kg = kg0 + (long)(kt * 64) * QKV_N;
        #pragma unroll
        for (int it = 0; it < 4; ++it) {
            const int rK = it * 16 + wsig * 4 + krl;
            __builtin_amdgcn_global_load_lds(GLOBAL_AS(kg + (long)rK * QKV_N + kswz),
                                             LDS_AS(&Ks[p][it * 2048 + wave * 512]), 16, 0, 0);
        }
    };
    auto stageV = [&](int kt) {
        const bf16* vg = vg0 + kt * 64;
        #pragma unroll
        for (int it = 0; it < 4; ++it) {
            const int dV = it * 32 + wave * 8 + vrl;
            __builtin_amdgcn_global_load_lds(GLOBAL_AS(vg + (long)dV * T_SEQ + vswz),
                                             LDS_AS(&Vs[it * 2048 + wave * 512]), 16, 0, 0);
        }
    };

    stageK(0, 0);

    const int qg = q0 + wave * 16 + l16;

    for (int kt = 0; kt <= iq; ++kt) {
        const int p = kt & 1;
        __syncthreads();                   // K[p] landed (vmcnt0); all Vs readers done
        stageV(kt);                        // V first (counted-wait relies on FIFO retire)
        if (kt < iq) stageK(p ^ 1, kt + 1);

        const int k0 = kt * 64;

        // S^T = K Q^T (rows = sigma'd kt, cols = q)
        floatx4 sT[4] = {};
        #pragma unroll
        for (int j2 = 0; j2 < 4; ++j2)
            #pragma unroll
            for (int ks = 0; ks < 4; ++ks) {
                bf16x8 kf = *(const bf16x8*)(&Ks[p][(j2 * 16 + l16) * 128 + (((ks * 4 + quad) ^ l16) * 8)]);
                sT[j2] = __builtin_amdgcn_mfma_f32_16x16x32_bf16(kf, qf[ks], sT[j2], 0, 0, 0);
            }

        // softmax numerators, fully in-register: this lane's element (j2,r)
        // is P(q = l16, kt = k0 + j2*16 + sigma(quad)*4 + r)
        const bool diag = (kt == iq);
        unsigned lov[4], hiv[4];
        #pragma unroll
        for (int j2 = 0; j2 < 4; ++j2) {
            float ev[4];
            #pragma unroll
            for (int r = 0; r < 4; ++r) {
                float x = __builtin_amdgcn_exp2f(sT[j2][r] * C1 - C2);
                if (diag && (k0 + j2 * 16 + sq4 + r > qg)) x = 0.f;
                ls += x;
                ev[r] = x;
            }
            asm("v_cvt_pk_bf16_f32 %0, %1, %2" : "=v"(lov[j2]) : "v"(ev[0]), "v"(ev[1]));
            asm("v_cvt_pk_bf16_f32 %0, %1, %2" : "=v"(hiv[j2]) : "v"(ev[2]), "v"(ev[3]));
        }

        // lane+-32 redistribution to PV A-operand layout
        bf16x8 pa[2];
        #pragma unroll
        for (int ks2 = 0; ks2 < 2; ++ks2) {
            auto wl = __builtin_amdgcn_permlane32_swap(lov[2 * ks2], lov[2 * ks2 + 1], false, false);
            auto wh = __builtin_amdgcn_permlane32_swap(hiv[2 * ks2], hiv[2 * ks2 + 1], false, false);
            union { unsigned w[4]; bf16x8 v; } u;
            u.w[0] = wl[0]; u.w[1] = wh[0]; u.w[2] = wl[1]; u.w[3] = wh[1];
            pa[ks2] = u.v;
        }

        // mid barrier: V[kt] landed (4 oldest loads retired), K[t+1] stays in flight
        if (kt < iq) asm volatile("s_waitcnt vmcnt(4)" ::: "memory");
        else         asm volatile("s_waitcnt vmcnt(0)" ::: "memory");
        __builtin_amdgcn_s_barrier();
        __builtin_amdgcn_sched_barrier(0);

        // O += P V
        #pragma unroll
        for (int ks2 = 0; ks2 < 2; ++ks2)
            #pragma unroll
            for (int vj = 0; vj < 8; ++vj) {
                const int d = vj * 16 + l16;
                bf16x8 vb = *(const bf16x8*)(&Vs[d * 64 + (((ks2 * 4 + quad) ^ (d & 7)) * 8)]);
                oacc[vj] = __builtin_amdgcn_mfma_f32_16x16x32_bf16(pa[ks2], vb, oacc[vj], 0, 0, 0);
            }
    }

    // total row sums: reduce over quads (lane l16 holds q-row l16's sum)
    ls += __shfl_xor(ls, 16); ls += __shfl_xor(ls, 32);
    float rinv[4];
    #pragma unroll
    for (int r = 0; r < 4; ++r) rinv[r] = 1.f / __shfl(ls, quad * 4 + r);

    #pragma unroll
    for (int vj = 0; vj < 8; ++vj)
        #pragma unroll
        for (int r = 0; r < 4; ++r) {
            const long row = q0 + wave * 16 + quad * 4 + r;
            qkv[row * (long)QKV_N + h * HD + vj * 16 + l16] = (bf16)(oacc[vj][r] * rinv[r]);
        }
}

// ---------------------------------------------------------------------------
extern "C" void kernel_launch(void* const* d_in, const int* in_sizes, int n_in,
                              void* d_out, int out_size, void* d_ws, size_t ws_size,
                              hipStream_t stream)
{
    const int* positions = (const int*)d_in[0];

    char* ws = (char*)d_ws;
    bf16* qkv  = (bf16*)(ws);              // [2048][6144]  25165824 B
    bf16* hb   = (bf16*)(ws + 25165824);   // [2048][2048]   8388608 B (dead after gemm1)
    bf16* vt   = hb;                       // [8][128][2048] 4194304 B (aliases hb)
    // o-proj split-K partials: live only after attn5 (hb/vt and wqb both dead)
    float* P0  = (float*)(ws + 25165824);  // [2048][2048] fp32 16777216 B
    float* P1  = (float*)(ws + 41943040);  // [2048][2048] fp32 16777216 B (ends at wob)
    bf16* wqb  = (bf16*)(ws + 33554432);   // [6144][2048]  25165824 B
    bf16* wob  = (bf16*)(ws + 58720256);   // [2048][4096]  16777216 B
    bf16* qnb  = (bf16*)(ws + 75497472);
    bf16* knb  = (bf16*)(ws + 75497728);
    int*  flag = (int*) (ws + 75497984);

    detect_dtype<<<dim3(1), dim3(64), 0, stream>>>((const unsigned short*)d_in[2], flag);
    convert_all<<<dim3(12289), dim3(256), 0, stream>>>(
        d_in[1], d_in[2], d_in[3], d_in[4], d_in[5],
        hb, wqb, wob, qnb, knb, flag);

    // QKV proj: 256^2 8-wave dbuf tiles, grid (8, 24) = 192 blocks.
    gemm8p<<<dim3(T_SEQ / 256, QKV_N / 256), dim3(512), 0, stream>>>(
        hb, wqb, qkv, QKV_N, HIDDEN, HIDDEN, HIDDEN);
    vtrans<<<dim3(T_SEQ / 64, NUM_KV), dim3(256), 0, stream>>>(qkv, vt);
    qkv_post<<<dim3(T_SEQ), dim3(256), 0, stream>>>(qkv, positions, qnb, knb);
    attn5<<<dim3(NUM_H, 32), dim3(256), 0, stream>>>(qkv, vt);
    // o-proj: split-K=2, 128x128 dbuf tiles, fp32 partials, then reduce.
    gemm_db<<<dim3(T_SEQ / 128, HIDDEN / 128, 2), dim3(256), 0, stream>>>(
        qkv, wob, P0, HIDDEN, Q_SIZE / 2, QKV_N, Q_SIZE);
    reduce2<<<dim3(4096), dim3(256), 0, stream>>>(P0, P1, d_out, flag);
}

// Round 4
// 324.441 us; speedup vs baseline: 1.2196x; 1.0159x over previous
//
#include <hip/hip_runtime.h>
#include <hip/hip_bf16.h>

#define T_SEQ   2048
#define HIDDEN  2048
#define NUM_H   32
#define NUM_KV  8
#define HD      128
#define Q_SIZE  4096
#define QKV_N   6144

typedef __bf16 bf16;
typedef __bf16 bf16x8 __attribute__((ext_vector_type(8)));
typedef __bf16 bf16x4 __attribute__((ext_vector_type(4)));
typedef float  floatx4 __attribute__((ext_vector_type(4)));

#define GLOBAL_AS(p) ((const __attribute__((address_space(1))) void*)(p))
#define LDS_AS(p)    ((__attribute__((address_space(3))) void*)(p))

// memory-clobber-wrapped barrier: blocks compiler memory reordering across it
#define BARRIER() do { asm volatile("" ::: "memory"); \
                       __builtin_amdgcn_s_barrier();  \
                       asm volatile("" ::: "memory"); } while (0)
#define VMCNT0() asm volatile("s_waitcnt vmcnt(0)" ::: "memory")
#define VMCNT2() asm volatile("s_waitcnt vmcnt(2)" ::: "memory")
#define VMCNT4() asm volatile("s_waitcnt vmcnt(4)" ::: "memory")
#define VMCNT6() asm volatile("s_waitcnt vmcnt(6)" ::: "memory")

// ---------------------------------------------------------------------------
// Dtype detection (fp32 vs bf16 inputs). flag=1 => bf16.
// ---------------------------------------------------------------------------
__global__ void detect_dtype(const unsigned short* __restrict__ wq, int* flagp)
{
    const int lane = threadIdx.x;   // 64 threads
    int cnt = 0;
    for (int i = lane; i < 512; i += 64) {
        int ef = (wq[i] >> 7) & 0xFF;
        if (ef >= 90 && ef <= 130) cnt++;
    }
    #pragma unroll
    for (int m = 32; m; m >>= 1) cnt += __shfl_xor(cnt, m);
    if (lane == 0) *flagp = (cnt >= 430) ? 1 : 0;
}

// ---------------------------------------------------------------------------
// Canonicalize all float inputs into bf16 workspace copies.
// ---------------------------------------------------------------------------
__global__ __launch_bounds__(256) void convert_all(
    const void* __restrict__ h, const void* __restrict__ wq,
    const void* __restrict__ wo_, const void* __restrict__ qn,
    const void* __restrict__ kn,
    bf16* __restrict__ hb, bf16* __restrict__ wqb, bf16* __restrict__ wob,
    bf16* __restrict__ qnb, bf16* __restrict__ knb, const int* flagp)
{
    long e = ((long)blockIdx.x * 256 + threadIdx.x) * 8;
    const void* src; bf16* dst; long off;
    if      (e < 4194304)  { src = h;   dst = hb;  off = e; }
    else if (e < 16777216) { src = wq;  dst = wqb; off = e - 4194304; }
    else if (e < 25165824) { src = wo_; dst = wob; off = e - 16777216; }
    else if (e < 25165952) { src = qn;  dst = qnb; off = e - 25165824; }
    else if (e < 25166080) { src = kn;  dst = knb; off = e - 25165952; }
    else return;

    if (*flagp) {
        *(bf16x8*)(dst + off) = *(const bf16x8*)((const bf16*)src + off);
    } else {
        const float* f = (const float*)src + off;
        bf16x8 v;
        #pragma unroll
        for (int i = 0; i < 8; ++i) v[i] = (bf16)f[i];
        *(bf16x8*)(dst + off) = v;
    }
}

// ---------------------------------------------------------------------------
// gemm8p: NT GEMM, 256x256 tile, BK=64, 8 waves (2M x 4N), 512 threads,
// 128 KB LDS. Full m201-style 8-phase schedule (2 K-tiles per iteration):
// each phase = { ds_read operand subtile | stage one half-tile pair (2
// global_load_lds) -> BAR -> 16 MFMA (setprio) -> BAR }. Counted vmcnt:
// (6) at ph2/ph6, (4) at ph4/ph8 (tail: 2/0) -- prefetch loads stay in
// flight across barriers, landing distance 2-3 phases. 16B-chunk XOR
// swizzle (chunk c at c^(row&7)) on the pre-swizzled global source +
// re-applied on ds_read (rule #21). Grid (N/256, M/256): flat%8 keys on
// the N-tile, so each XCD holds 3 B-panels L2-resident and streams A.
// ---------------------------------------------------------------------------
__global__ __launch_bounds__(512, 2) void gemm8p(
    const bf16* __restrict__ A, const bf16* __restrict__ B,
    bf16* __restrict__ C, int N, int K, int lda, int ldb)
{
    __shared__ bf16 As[2][2][128 * 64];   // [dbuf][Mhalf][row*64+col], swizzled
    __shared__ bf16 Bs[2][2][128 * 64];   // [dbuf][Nhalf][...]

    const int tid  = threadIdx.x;
    const int wave = tid >> 6, lane = tid & 63;
    const int quad = lane >> 4, l16 = lane & 15;
    const int wm = wave >> 2;            // M half this wave computes/reads
    const int wn = wave & 3;             // N quarter
    const int wh = wn >> 1;              // B half this wave reads
    const int bro = (wn & 1) * 64;       // row offset within B half
    const long baseN = (long)blockIdx.x * 256;
    const long baseM = (long)blockIdx.y * 256;

    // staging: unit = 64 rows x 64 cols = 8KB = 1 load/thread.
    // thread tid: local row r=tid>>3, slot=tid&7, global chunk = slot^(r&7).
    const int sr  = tid >> 3;
    const int sgc = ((tid & 7) ^ (sr & 7)) * 8;

    // PB(p,h,t): B half h (128 rows) of K-tile t -> Bs[p][h] (2 loads)
    auto stagePB = [&](int p, int h, int t) {
        const long kc = (long)t * 64;
        const bf16* src = B + (baseN + h * 128 + sr) * (long)ldb + kc + sgc;
        __builtin_amdgcn_global_load_lds(GLOBAL_AS(src),
            LDS_AS(&Bs[p][h][wave * 512]), 16, 0, 0);
        __builtin_amdgcn_global_load_lds(GLOBAL_AS(src + 64 * (long)ldb),
            LDS_AS(&Bs[p][h][4096 + wave * 512]), 16, 0, 0);
    };
    // PA(p,g,t): A row-group g (rows g*64..+63) of BOTH halves (2 loads)
    auto stagePA = [&](int p, int g, int t) {
        const long kc = (long)t * 64;
        const bf16* src = A + (baseM + g * 64 + sr) * (long)lda + kc + sgc;
        __builtin_amdgcn_global_load_lds(GLOBAL_AS(src),
            LDS_AS(&As[p][0][g * 4096 + wave * 512]), 16, 0, 0);
        __builtin_amdgcn_global_load_lds(GLOBAL_AS(src + 128 * (long)lda),
            LDS_AS(&As[p][1][g * 4096 + wave * 512]), 16, 0, 0);
    };

    floatx4 acc[8][4] = {};   // [mf 0..7][nf 0..3]
    bf16x8 af[4][2], bf0[2][2], bf1[2][2];

    auto rdAf = [&](int p, int g) {
        #pragma unroll
        for (int mf = 0; mf < 4; ++mf)
            #pragma unroll
            for (int ks = 0; ks < 2; ++ks) {
                const int r = g * 64 + mf * 16 + l16;
                af[mf][ks] = *(const bf16x8*)(&As[p][wm][r * 64 + (((ks * 4 + quad) ^ (r & 7)) * 8)]);
            }
    };
    auto rdB0 = [&](int p) {
        #pragma unroll
        for (int nf = 0; nf < 2; ++nf)
            #pragma unroll
            for (int ks = 0; ks < 2; ++ks) {
                const int r = bro + nf * 16 + l16;
                bf0[nf][ks] = *(const bf16x8*)(&Bs[p][wh][r * 64 + (((ks * 4 + quad) ^ (r & 7)) * 8)]);
            }
    };
    auto rdB1 = [&](int p) {
        #pragma unroll
        for (int nf = 0; nf < 2; ++nf)
            #pragma unroll
            for (int ks = 0; ks < 2; ++ks) {
                const int r = bro + (nf + 2) * 16 + l16;
                bf1[nf][ks] = *(const bf16x8*)(&Bs[p][wh][r * 64 + (((ks * 4 + quad) ^ (r & 7)) * 8)]);
            }
    };
    auto mmQ = [&](int mo, int no, bf16x8 (&bfr)[2][2]) {
        __builtin_amdgcn_s_setprio(1);
        #pragma unroll
        for (int mf = 0; mf < 4; ++mf)
            #pragma unroll
            for (int nf = 0; nf < 2; ++nf)
                #pragma unroll
                for (int ks = 0; ks < 2; ++ks)
                    acc[mo + mf][no + nf] = __builtin_amdgcn_mfma_f32_16x16x32_bf16(
                        af[mf][ks], bfr[nf][ks], acc[mo + mf][no + nf], 0, 0, 0);
        __builtin_amdgcn_s_setprio(0);
    };

    // prologue: tile0 fully + PB0(1); drain tile0 (leave PB0(1) in flight)
    stagePB(0, 0, 0); stagePB(0, 1, 0); stagePA(0, 0, 0); stagePA(0, 1, 0);
    stagePB(1, 0, 1);
    VMCNT2();
    BARRIER();

    const int NT2 = K / 128;   // iterations of 2 K-tiles
    for (int j = 0; j < NT2; ++j) {
        const int t1 = 2 * j + 1;
        const bool more = (j + 1 < NT2);

        // ph1: Q00 of buf0
        rdAf(0, 0); rdB0(0);
        stagePB(1, 1, t1);
        BARRIER(); __builtin_amdgcn_sched_barrier(0);
        mmQ(0, 0, bf0);
        BARRIER();
        // ph2: Q01 of buf0
        rdB1(0);
        stagePA(1, 0, t1);
        VMCNT6();
        BARRIER(); __builtin_amdgcn_sched_barrier(0);
        mmQ(0, 2, bf1);
        BARRIER();
        // ph3: Q10 of buf0
        rdAf(0, 1);
        stagePA(1, 1, t1);
        BARRIER(); __builtin_amdgcn_sched_barrier(0);
        mmQ(4, 0, bf0);
        BARRIER();
        // ph4: Q11 of buf0
        if (more) { stagePB(0, 0, t1 + 1); VMCNT4(); } else { VMCNT2(); }
        BARRIER(); __builtin_amdgcn_sched_barrier(0);
        mmQ(4, 2, bf1);
        BARRIER();
        // ph5: Q00 of buf1
        rdAf(1, 0); rdB0(1);
        if (more) stagePB(0, 1, t1 + 1);
        BARRIER(); __builtin_amdgcn_sched_barrier(0);
        mmQ(0, 0, bf0);
        BARRIER();
        // ph6: Q01 of buf1
        rdB1(1);
        if (more) { stagePA(0, 0, t1 + 1); VMCNT6(); } else { VMCNT0(); }
        BARRIER(); __builtin_amdgcn_sched_barrier(0);
        mmQ(0, 2, bf1);
        BARRIER();
        // ph7: Q10 of buf1
        rdAf(1, 1);
        if (more) stagePA(0, 1, t1 + 1);
        BARRIER(); __builtin_amdgcn_sched_barrier(0);
        mmQ(4, 0, bf0);
        BARRIER();
        // ph8: Q11 of buf1
        if (more) { stagePB(1, 0, t1 + 2); VMCNT4(); }
        BARRIER(); __builtin_amdgcn_sched_barrier(0);
        mmQ(4, 2, bf1);
        BARRIER();
    }

    #pragma unroll
    for (int i = 0; i < 8; ++i)
        #pragma unroll
        for (int j = 0; j < 4; ++j)
            #pragma unroll
            for (int r = 0; r < 4; ++r) {
                long row = baseM + wm * 128 + i * 16 + quad * 4 + r;
                long col = baseN + wn * 64 + j * 16 + l16;
                C[row * (long)N + col] = (bf16)acc[i][j][r];
            }
}

// ---------------------------------------------------------------------------
// gemm_db: NT GEMM 128x128, double-buffered 2-phase, split-K via blockIdx.z.
// fp32 partials [z][M][N]. (o-proj; proven.)
// ---------------------------------------------------------------------------
__global__ __launch_bounds__(256) void gemm_db(
    const bf16* __restrict__ A, const bf16* __restrict__ B,
    float* __restrict__ Cp, int N, int Kd, int lda, int ldb)
{
    __shared__ bf16 As[2][128 * 32];
    __shared__ bf16 Bs[2][128 * 32];

    const int tid  = threadIdx.x;
    const int wave = tid >> 6, lane = tid & 63;
    const int quad = lane >> 4, l16 = lane & 15;
    const int wm = (wave & 1) * 64, wn = (wave >> 1) * 64;
    const long baseM = (long)blockIdx.x * 128;
    const long baseN = (long)blockIdx.y * 128;
    const long koff  = (long)blockIdx.z * Kd;

    const int  srow = wave * 16 + (lane >> 2);
    const int  scol = (lane & 3) * 8;
    const long aoff0 = (baseM + srow) * (long)lda + koff + scol;
    const long aoff1 = (baseM + 64 + srow) * (long)lda + koff + scol;
    const long boff0 = (baseN + srow) * (long)ldb + koff + scol;
    const long boff1 = (baseN + 64 + srow) * (long)ldb + koff + scol;
    const int  lds0 = wave * 512;
    const int  lds1 = 2048 + wave * 512;

    auto stage = [&](int p, int k0) {
        __builtin_amdgcn_global_load_lds(GLOBAL_AS(A + aoff0 + k0), LDS_AS(As[p] + lds0), 16, 0, 0);
        __builtin_amdgcn_global_load_lds(GLOBAL_AS(A + aoff1 + k0), LDS_AS(As[p] + lds1), 16, 0, 0);
        __builtin_amdgcn_global_load_lds(GLOBAL_AS(B + boff0 + k0), LDS_AS(Bs[p] + lds0), 16, 0, 0);
        __builtin_amdgcn_global_load_lds(GLOBAL_AS(B + boff1 + k0), LDS_AS(Bs[p] + lds1), 16, 0, 0);
    };

    floatx4 acc[4][4] = {};

    stage(0, 0);
    asm volatile("s_waitcnt vmcnt(0)" ::: "memory");
    __builtin_amdgcn_s_barrier();

    int cur = 0;
    for (int k0 = 0; k0 < Kd; k0 += 32) {
        if (k0 + 32 < Kd) stage(cur ^ 1, k0 + 32);   // prefetch next tile
        __builtin_amdgcn_sched_barrier(0);           // pin load issue before compute

        bf16x8 af[4], bfr[4];
        #pragma unroll
        for (int i = 0; i < 4; ++i)
            af[i] = *(const bf16x8*)(As[cur] + (wm + i * 16 + l16) * 32 + quad * 8);
        #pragma unroll
        for (int j = 0; j < 4; ++j)
            bfr[j] = *(const bf16x8*)(Bs[cur] + (wn + j * 16 + l16) * 32 + quad * 8);

        #pragma unroll
        for (int i = 0; i < 4; ++i)
            #pragma unroll
            for (int j = 0; j < 4; ++j)
                acc[i][j] = __builtin_amdgcn_mfma_f32_16x16x32_bf16(af[i], bfr[j], acc[i][j], 0, 0, 0);

        asm volatile("s_waitcnt vmcnt(0)" ::: "memory");  // next tile landed
        __builtin_amdgcn_s_barrier();                     // all readers of cur done
        cur ^= 1;
    }

    const long Mrows = (long)gridDim.x * 128;
    float* C = Cp + (long)blockIdx.z * Mrows * N;
    #pragma unroll
    for (int i = 0; i < 4; ++i)
        #pragma unroll
        for (int j = 0; j < 4; ++j)
            #pragma unroll
            for (int r = 0; r < 4; ++r) {
                long row = baseM + wm + i * 16 + quad * 4 + r;
                long col = baseN + wn + j * 16 + l16;
                C[row * (long)N + col] = acc[i][j][r];
            }
}

// ---------------------------------------------------------------------------
// reduce2: out = P0 + P1, cast per flag. HBM-bound.
// ---------------------------------------------------------------------------
__global__ __launch_bounds__(256) void reduce2(
    const float* __restrict__ P0, const float* __restrict__ P1,
    void* __restrict__ out, const int* flagp)
{
    long i = ((long)blockIdx.x * 256 + threadIdx.x) * 4;
    floatx4 a = *(const floatx4*)(P0 + i);
    floatx4 b = *(const floatx4*)(P1 + i);
    floatx4 s = a + b;
    if (*flagp) {
        bf16x4 o;
        #pragma unroll
        for (int r = 0; r < 4; ++r) o[r] = (bf16)s[r];
        *(bf16x4*)((bf16*)out + i) = o;
    } else {
        *(floatx4*)((float*)out + i) = s;
    }
}

// ---------------------------------------------------------------------------
// In-place RMSNorm + RoPE on q/k sections of qkv[t][6144].
// ---------------------------------------------------------------------------
__global__ __launch_bounds__(256) void qkv_post(
    bf16* __restrict__ qkv, const int* __restrict__ positions,
    const bf16* __restrict__ qnw, const bf16* __restrict__ knw)
{
    const int t = blockIdx.x;
    const int tid = threadIdx.x, wave = tid >> 6, lane = tid & 63;
    const float pos = (float)positions[t];

    const float inv = expf(-(float)lane * (float)(9.210340371976184 / 64.0));
    float sn, cs;
    sincosf(pos * inv, &sn, &cs);

    bf16* row = qkv + (long)t * QKV_N;

    for (int u = wave; u < 40; u += 4) {
        bf16* p       = (u < 32) ? row + u * HD : row + Q_SIZE + (u - 32) * HD;
        const bf16* w = (u < 32) ? qnw : knw;
        float x1 = (float)p[lane], x2 = (float)p[lane + 64];
        float ss = x1 * x1 + x2 * x2;
        #pragma unroll
        for (int m = 32; m; m >>= 1) ss += __shfl_xor(ss, m);
        float rr = rsqrtf(ss * (1.f / 128.f) + 1e-6f);
        float y1 = x1 * rr * (float)w[lane];
        float y2 = x2 * rr * (float)w[lane + 64];
        p[lane]      = (bf16)(y1 * cs - y2 * sn);
        p[lane + 64] = (bf16)(y2 * cs + y1 * sn);
    }
}

// ---------------------------------------------------------------------------
// V transpose: vt[kvh][d][t] from qkv[t][5120+kvh*128+d].
// ---------------------------------------------------------------------------
__global__ __launch_bounds__(256) void vtrans(const bf16* __restrict__ qkv,
                                              bf16* __restrict__ vt)
{
    __shared__ bf16 tile[64][136];
    const int t0 = blockIdx.x * 64, kvh = blockIdx.y, tid = threadIdx.x;

    const int rl = tid >> 4, c8 = (tid & 15) * 8;
    const bf16* src = qkv + (long)t0 * QKV_N + 5120 + kvh * HD;
    #pragma unroll
    for (int it = 0; it < 4; ++it) {
        int r = it * 16 + rl;
        *(bf16x8*)(&tile[r][c8]) = *(const bf16x8*)(src + (long)r * QKV_N + c8);
    }
    __syncthreads();

    const int d = tid >> 1, tb = (tid & 1) * 32;
    bf16* dst = vt + ((long)kvh * HD + d) * T_SEQ + t0 + tb;
    #pragma unroll
    for (int it = 0; it < 4; ++it) {
        bf16x8 v;
        #pragma unroll
        for (int j = 0; j < 8; ++j) v[j] = tile[tb + it * 8 + j][d];
        *(bf16x8*)(dst + it * 8) = v;
    }
}

// ---------------------------------------------------------------------------
// attn5: unpaired 64-row q-tiles, grid (head, 32) with iq = 31 - blockIdx.y
// (LPT). 1024 blocks; LDS 48KB -> 3 blocks/CU. Counted vmcnt(4) mid-iter
// keeps the K[t+1] prefetch in flight. P fully in-register via sigma'd K
// staging + v_cvt_pk_bf16_f32 + permlane32_swap.
// ---------------------------------------------------------------------------
__global__ __launch_bounds__(256, 3) void attn5(bf16* qkv, const bf16* __restrict__ vt)
{
    __shared__ bf16 Ks[2][64 * 128];   // [kt-row][d], 16B chunk c at c^(row&15), rows sigma'd
    __shared__ bf16 Vs[128 * 64];      // [d][kt-row], 16B chunk c at c^(d&7), single buffer

    const int tid  = threadIdx.x, wave = tid >> 6, lane = tid & 63;
    const int quad = lane >> 4, l16 = lane & 15;
    const int h = blockIdx.x, kvh = h >> 2;
    const int iq = 31 - blockIdx.y;    // tile index, longest first (LPT)
    const int q0 = iq * 64;

    const float C1 = 0.12753236f;      // 128^-0.5 * log2(e)
    const float C2 = 17.312340f;       // 12 * log2(e)

    bf16x8 qf[4];
    {
        const bf16* qa = qkv + (long)(q0 + wave * 16 + l16) * QKV_N + h * HD + quad * 8;
        #pragma unroll
        for (int ks = 0; ks < 4; ++ks) qf[ks] = *(const bf16x8*)(qa + ks * 32);
    }

    floatx4 oacc[8] = {};
    float ls = 0.f;

    const int krl = lane >> 4, kc = lane & 15;
    const int vrl = lane >> 3, vc = lane & 7;
    const int kswz = (kc ^ (wave * 4 + krl)) * 8;
    const int vswz = (vc ^ (vrl & 7)) * 8;
    const int wsig = ((wave & 1) << 1) | (wave >> 1);           // sigma(wave): 1<->2
    const int sq4  = (((quad & 1) << 1) | (quad >> 1)) << 2;    // sigma(quad)*4

    const bf16* kg0 = qkv + Q_SIZE + kvh * HD;
    const bf16* vg0 = vt + (long)kvh * HD * T_SEQ;

    auto stageK = [&](int p, int kt) {
        const bf16* kg = kg0 + (long)(kt * 64) * QKV_N;
        #pragma unroll
        for (int it = 0; it < 4; ++it) {
            const int rK = it * 16 + wsig * 4 + krl;
            __builtin_amdgcn_global_load_lds(GLOBAL_AS(kg + (long)rK * QKV_N + kswz),
                                             LDS_AS(&Ks[p][it * 2048 + wave * 512]), 16, 0, 0);
        }
    };
    auto stageV = [&](int kt) {
        const bf16* vg = vg0 + kt * 64;
        #pragma unroll
        for (int it = 0; it < 4; ++it) {
            const int dV = it * 32 + wave * 8 + vrl;
            __builtin_amdgcn_global_load_lds(GLOBAL_AS(vg + (long)dV * T_SEQ + vswz),
                                             LDS_AS(&Vs[it * 2048 + wave * 512]), 16, 0, 0);
        }
    };

    stageK(0, 0);

    const int qg = q0 + wave * 16 + l16;

    for (int kt = 0; kt <= iq; ++kt) {
        const int p = kt & 1;
        __syncthreads();                   // K[p] landed (vmcnt0); all Vs readers done
        stageV(kt);                        // V first (counted-wait relies on FIFO retire)
        if (kt < iq) stageK(p ^ 1, kt + 1);

        const int k0 = kt * 64;

        floatx4 sT[4] = {};
        #pragma unroll
        for (int j2 = 0; j2 < 4; ++j2)
            #pragma unroll
            for (int ks = 0; ks < 4; ++ks) {
                bf16x8 kf = *(const bf16x8*)(&Ks[p][(j2 * 16 + l16) * 128 + (((ks * 4 + quad) ^ l16) * 8)]);
                sT[j2] = __builtin_amdgcn_mfma_f32_16x16x32_bf16(kf, qf[ks], sT[j2], 0, 0, 0);
            }

        const bool diag = (kt == iq);
        unsigned lov[4], hiv[4];
        #pragma unroll
        for (int j2 = 0; j2 < 4; ++j2) {
            float ev[4];
            #pragma unroll
            for (int r = 0; r < 4; ++r) {
                float x = __builtin_amdgcn_exp2f(sT[j2][r] * C1 - C2);
                if (diag && (k0 + j2 * 16 + sq4 + r > qg)) x = 0.f;
                ls += x;
                ev[r] = x;
            }
            asm("v_cvt_pk_bf16_f32 %0, %1, %2" : "=v"(lov[j2]) : "v"(ev[0]), "v"(ev[1]));
            asm("v_cvt_pk_bf16_f32 %0, %1, %2" : "=v"(hiv[j2]) : "v"(ev[2]), "v"(ev[3]));
        }

        bf16x8 pa[2];
        #pragma unroll
        for (int ks2 = 0; ks2 < 2; ++ks2) {
            auto wl = __builtin_amdgcn_permlane32_swap(lov[2 * ks2], lov[2 * ks2 + 1], false, false);
            auto wh = __builtin_amdgcn_permlane32_swap(hiv[2 * ks2], hiv[2 * ks2 + 1], false, false);
            union { unsigned w[4]; bf16x8 v; } u;
            u.w[0] = wl[0]; u.w[1] = wh[0]; u.w[2] = wl[1]; u.w[3] = wh[1];
            pa[ks2] = u.v;
        }

        if (kt < iq) asm volatile("s_waitcnt vmcnt(4)" ::: "memory");
        else         asm volatile("s_waitcnt vmcnt(0)" ::: "memory");
        __builtin_amdgcn_s_barrier();
        __builtin_amdgcn_sched_barrier(0);

        #pragma unroll
        for (int ks2 = 0; ks2 < 2; ++ks2)
            #pragma unroll
            for (int vj = 0; vj < 8; ++vj) {
                const int d = vj * 16 + l16;
                bf16x8 vb = *(const bf16x8*)(&Vs[d * 64 + (((ks2 * 4 + quad) ^ (d & 7)) * 8)]);
                oacc[vj] = __builtin_amdgcn_mfma_f32_16x16x32_bf16(pa[ks2], vb, oacc[vj], 0, 0, 0);
            }
    }

    ls += __shfl_xor(ls, 16); ls += __shfl_xor(ls, 32);
    float rinv[4];
    #pragma unroll
    for (int r = 0; r < 4; ++r) rinv[r] = 1.f / __shfl(ls, quad * 4 + r);

    #pragma unroll
    for (int vj = 0; vj < 8; ++vj)
        #pragma unroll
        for (int r = 0; r < 4; ++r) {
            const long row = q0 + wave * 16 + quad * 4 + r;
            qkv[row * (long)QKV_N + h * HD + vj * 16 + l16] = (bf16)(oacc[vj][r] * rinv[r]);
        }
}

// ---------------------------------------------------------------------------
extern "C" void kernel_launch(void* const* d_in, const int* in_sizes, int n_in,
                              void* d_out, int out_size, void* d_ws, size_t ws_size,
                              hipStream_t stream)
{
    const int* positions = (const int*)d_in[0];

    char* ws = (char*)d_ws;
    bf16* qkv  = (bf16*)(ws);              // [2048][6144]  25165824 B
    bf16* hb   = (bf16*)(ws + 25165824);   // [2048][2048]   8388608 B (dead after gemm1)
    bf16* vt   = hb;                       // [8][128][2048] 4194304 B (aliases hb)
    // o-proj split-K partials: live only after attn5 (hb/vt and wqb both dead)
    float* P0  = (float*)(ws + 25165824);  // [2048][2048] fp32 16777216 B
    float* P1  = (float*)(ws + 41943040);  // [2048][2048] fp32 16777216 B (ends at wob)
    bf16* wqb  = (bf16*)(ws + 33554432);   // [6144][2048]  25165824 B
    bf16* wob  = (bf16*)(ws + 58720256);   // [2048][4096]  16777216 B
    bf16* qnb  = (bf16*)(ws + 75497472);
    bf16* knb  = (bf16*)(ws + 75497728);
    int*  flag = (int*) (ws + 75497984);

    detect_dtype<<<dim3(1), dim3(64), 0, stream>>>((const unsigned short*)d_in[2], flag);
    convert_all<<<dim3(12289), dim3(256), 0, stream>>>(
        d_in[1], d_in[2], d_in[3], d_in[4], d_in[5],
        hb, wqb, wob, qnb, knb, flag);

    // QKV proj: 256^2 8-phase dbuf tiles, grid (24, 8) -> B-panels per XCD.
    gemm8p<<<dim3(QKV_N / 256, T_SEQ / 256), dim3(512), 0, stream>>>(
        hb, wqb, qkv, QKV_N, HIDDEN, HIDDEN, HIDDEN);
    vtrans<<<dim3(T_SEQ / 64, NUM_KV), dim3(256), 0, stream>>>(qkv, vt);
    qkv_post<<<dim3(T_SEQ), dim3(256), 0, stream>>>(qkv, positions, qnb, knb);
    attn5<<<dim3(NUM_H, 32), dim3(256), 0, stream>>>(qkv, vt);
    // o-proj: split-K=2, 128x128 dbuf tiles, fp32 partials, then reduce.
    gemm_db<<<dim3(T_SEQ / 128, HIDDEN / 128, 2), dim3(256), 0, stream>>>(
        qkv, wob, P0, HIDDEN, Q_SIZE / 2, QKV_N, Q_SIZE);
    reduce2<<<dim3(4096), dim3(256), 0, stream>>>(P0, P1, d_out, flag);
}

// Round 5
// 318.957 us; speedup vs baseline: 1.2406x; 1.0172x over previous
//
#include <hip/hip_runtime.h>
#include <hip/hip_bf16.h>

#define T_SEQ   2048
#define HIDDEN  2048
#define NUM_H   32
#define NUM_KV  8
#define HD      128
#define Q_SIZE  4096
#define QKV_N   6144

typedef __bf16 bf16;
typedef __bf16 bf16x8 __attribute__((ext_vector_type(8)));
typedef __bf16 bf16x4 __attribute__((ext_vector_type(4)));
typedef float  floatx4 __attribute__((ext_vector_type(4)));

#define GLOBAL_AS(p) ((const __attribute__((address_space(1))) void*)(p))
#define LDS_AS(p)    ((__attribute__((address_space(3))) void*)(p))

// memory-clobber-wrapped barrier: blocks compiler memory reordering across it
#define BARRIER() do { asm volatile("" ::: "memory"); \
                       __builtin_amdgcn_s_barrier();  \
                       asm volatile("" ::: "memory"); } while (0)
#define VMCNT(n) asm volatile("s_waitcnt vmcnt(" #n ")" ::: "memory")

// ---------------------------------------------------------------------------
// Dtype detection (fp32 vs bf16 inputs). flag=1 => bf16.
// ---------------------------------------------------------------------------
__global__ void detect_dtype(const unsigned short* __restrict__ wq, int* flagp)
{
    const int lane = threadIdx.x;   // 64 threads
    int cnt = 0;
    for (int i = lane; i < 512; i += 64) {
        int ef = (wq[i] >> 7) & 0xFF;
        if (ef >= 90 && ef <= 130) cnt++;
    }
    #pragma unroll
    for (int m = 32; m; m >>= 1) cnt += __shfl_xor(cnt, m);
    if (lane == 0) *flagp = (cnt >= 430) ? 1 : 0;
}

// ---------------------------------------------------------------------------
// Canonicalize all float inputs into bf16 workspace copies.
// ---------------------------------------------------------------------------
__global__ __launch_bounds__(256) void convert_all(
    const void* __restrict__ h, const void* __restrict__ wq,
    const void* __restrict__ wo_, const void* __restrict__ qn,
    const void* __restrict__ kn,
    bf16* __restrict__ hb, bf16* __restrict__ wqb, bf16* __restrict__ wob,
    bf16* __restrict__ qnb, bf16* __restrict__ knb, const int* flagp)
{
    long e = ((long)blockIdx.x * 256 + threadIdx.x) * 8;
    const void* src; bf16* dst; long off;
    if      (e < 4194304)  { src = h;   dst = hb;  off = e; }
    else if (e < 16777216) { src = wq;  dst = wqb; off = e - 4194304; }
    else if (e < 25165824) { src = wo_; dst = wob; off = e - 16777216; }
    else if (e < 25165952) { src = qn;  dst = qnb; off = e - 25165824; }
    else if (e < 25166080) { src = kn;  dst = knb; off = e - 25165952; }
    else return;

    if (*flagp) {
        *(bf16x8*)(dst + off) = *(const bf16x8*)((const bf16*)src + off);
    } else {
        const float* f = (const float*)src + off;
        bf16x8 v;
        #pragma unroll
        for (int i = 0; i < 8; ++i) v[i] = (bf16)f[i];
        *(bf16x8*)(dst + off) = v;
    }
}

// ---------------------------------------------------------------------------
// gemm8p: NT GEMM, 256(M) x 192(N) tile, BK=64, 8 waves (2M x 4N, per-wave
// 128x48), 512 threads, 112 KB LDS. Same verified 8-phase counted-vmcnt
// schedule as the 256^2 version, retiled so grid (N/192, M/256) = (32, 8)
// = 256 blocks = FULL chip (256^2 left 64 CUs idle at 192 blocks).
// Staging units: A = 2 calls x 2 loads (64-row group of both M-halves),
// B = 3 calls x 1 load (64-row units of a single [192][64] array).
// Ledger (steady state): vmcnt(5)@ph2, (3)@ph4, (5)@ph6, (3)@ph8;
// tail iteration: 5/2/0/-. All reads have 2-3-phase landing distance;
// all LDS overwrites are >=1 barrier after the region's last read.
// 16B-chunk XOR swizzle (chunk c at c^(row&7)) on the pre-swizzled global
// source + re-applied on ds_read (rule #21).
// ---------------------------------------------------------------------------
__global__ __launch_bounds__(512, 2) void gemm8p(
    const bf16* __restrict__ A, const bf16* __restrict__ B,
    bf16* __restrict__ C, int N, int K, int lda, int ldb)
{
    __shared__ bf16 As[2][2][128 * 64];   // [dbuf][Mhalf][row*64+col], swizzled
    __shared__ bf16 Bs[2][192 * 64];      // [dbuf][row*64+col], row = C-col idx

    const int tid  = threadIdx.x;
    const int wave = tid >> 6, lane = tid & 63;
    const int quad = lane >> 4, l16 = lane & 15;
    const int wm = wave >> 2;            // M half this wave computes/reads
    const int wn = wave & 3;             // N quarter (48 cols)
    const long baseN = (long)blockIdx.x * 192;
    const long baseM = (long)blockIdx.y * 256;

    // staging: unit = 64 rows x 64 cols = 8KB = 1 load/thread.
    // thread tid: unit row r=tid>>3, slot=tid&7, global chunk = slot^(r&7).
    const int sr  = tid >> 3;
    const int sgc = ((tid & 7) ^ (sr & 7)) * 8;

    // PA(p,g,t): A row-group g (rows g*64..+63) of BOTH M-halves (2 loads)
    auto stagePA = [&](int p, int g, int t) {
        const long kc = (long)t * 64;
        const bf16* src = A + (baseM + g * 64 + sr) * (long)lda + kc + sgc;
        __builtin_amdgcn_global_load_lds(GLOBAL_AS(src),
            LDS_AS(&As[p][0][g * 4096 + wave * 512]), 16, 0, 0);
        __builtin_amdgcn_global_load_lds(GLOBAL_AS(src + 128 * (long)lda),
            LDS_AS(&As[p][1][g * 4096 + wave * 512]), 16, 0, 0);
    };
    // PBu(p,u,t): B rows u*64..+63 (1 load)
    auto stagePBu = [&](int p, int u, int t) {
        const long kc = (long)t * 64;
        const bf16* src = B + (baseN + u * 64 + sr) * (long)ldb + kc + sgc;
        __builtin_amdgcn_global_load_lds(GLOBAL_AS(src),
            LDS_AS(&Bs[p][u * 4096 + wave * 512]), 16, 0, 0);
    };

    floatx4 acc[8][3] = {};   // [mf 0..7][nf 0..2]
    bf16x8 af[4][2], bf01[2][2], bf2[2];

    auto rdAf = [&](int p, int g) {
        #pragma unroll
        for (int mf = 0; mf < 4; ++mf)
            #pragma unroll
            for (int ks = 0; ks < 2; ++ks) {
                const int r = g * 64 + mf * 16 + l16;
                af[mf][ks] = *(const bf16x8*)(&As[p][wm][r * 64 + (((ks * 4 + quad) ^ (r & 7)) * 8)]);
            }
    };
    auto rdB01 = [&](int p) {
        #pragma unroll
        for (int nf = 0; nf < 2; ++nf)
            #pragma unroll
            for (int ks = 0; ks < 2; ++ks) {
                const int r = wn * 48 + nf * 16 + l16;
                bf01[nf][ks] = *(const bf16x8*)(&Bs[p][r * 64 + (((ks * 4 + quad) ^ (r & 7)) * 8)]);
            }
    };
    auto rdB2 = [&](int p) {
        #pragma unroll
        for (int ks = 0; ks < 2; ++ks) {
            const int r = wn * 48 + 32 + l16;
            bf2[ks] = *(const bf16x8*)(&Bs[p][r * 64 + (((ks * 4 + quad) ^ (r & 7)) * 8)]);
        }
    };
    // 16-MFMA quadrant: rows mo..mo+63 x cols 0..31
    auto mmQ2 = [&](int mo) {
        __builtin_amdgcn_s_setprio(1);
        #pragma unroll
        for (int mf = 0; mf < 4; ++mf)
            #pragma unroll
            for (int nf = 0; nf < 2; ++nf)
                #pragma unroll
                for (int ks = 0; ks < 2; ++ks)
                    acc[mo + mf][nf] = __builtin_amdgcn_mfma_f32_16x16x32_bf16(
                        af[mf][ks], bf01[nf][ks], acc[mo + mf][nf], 0, 0, 0);
        __builtin_amdgcn_s_setprio(0);
    };
    // 8-MFMA quadrant: rows mo..mo+63 x cols 32..47
    auto mmQ1 = [&](int mo) {
        __builtin_amdgcn_s_setprio(1);
        #pragma unroll
        for (int mf = 0; mf < 4; ++mf)
            #pragma unroll
            for (int ks = 0; ks < 2; ++ks)
                acc[mo + mf][2] = __builtin_amdgcn_mfma_f32_16x16x32_bf16(
                    af[mf][ks], bf2[ks], acc[mo + mf][2], 0, 0, 0);
        __builtin_amdgcn_s_setprio(0);
    };

    // prologue: tile0 fully (7 loads) + PBu0 of tile1; drain tile0
    stagePBu(0, 0, 0); stagePBu(0, 1, 0); stagePBu(0, 2, 0);
    stagePA(0, 0, 0);  stagePA(0, 1, 0);
    stagePBu(1, 0, 1);
    VMCNT(1);
    BARRIER();

    const int NT2 = K / 128;   // iterations of 2 K-tiles
    for (int j = 0; j < NT2; ++j) {
        const int t1 = 2 * j + 1;
        const bool more = (j + 1 < NT2);

        // ph1: rows 0-63 x cols 0-31 of buf0
        rdAf(0, 0); rdB01(0);
        stagePBu(1, 1, t1); stagePBu(1, 2, t1);
        BARRIER(); __builtin_amdgcn_sched_barrier(0);
        mmQ2(0);
        BARRIER();
        // ph2: rows 0-63 x cols 32-47
        rdB2(0);
        stagePA(1, 0, t1);
        VMCNT(5);
        BARRIER(); __builtin_amdgcn_sched_barrier(0);
        mmQ1(0);
        BARRIER();
        // ph3: rows 64-127 x cols 0-31
        rdAf(0, 1);
        stagePA(1, 1, t1);
        BARRIER(); __builtin_amdgcn_sched_barrier(0);
        mmQ2(4);
        BARRIER();
        // ph4: rows 64-127 x cols 32-47
        if (more) { stagePBu(0, 0, t1 + 1); VMCNT(3); } else { VMCNT(2); }
        BARRIER(); __builtin_amdgcn_sched_barrier(0);
        mmQ1(4);
        BARRIER();
        // ph5: buf1, rows 0-63 x cols 0-31
        rdAf(1, 0); rdB01(1);
        if (more) { stagePBu(0, 1, t1 + 1); stagePBu(0, 2, t1 + 1); }
        BARRIER(); __builtin_amdgcn_sched_barrier(0);
        mmQ2(0);
        BARRIER();
        // ph6: buf1, rows 0-63 x cols 32-47
        rdB2(1);
        if (more) { stagePA(0, 0, t1 + 1); VMCNT(5); } else { VMCNT(0); }
        BARRIER(); __builtin_amdgcn_sched_barrier(0);
        mmQ1(0);
        BARRIER();
        // ph7: buf1, rows 64-127 x cols 0-31
        rdAf(1, 1);
        if (more) stagePA(0, 1, t1 + 1);
        BARRIER(); __builtin_amdgcn_sched_barrier(0);
        mmQ2(4);
        BARRIER();
        // ph8: buf1, rows 64-127 x cols 32-47
        if (more) { stagePBu(1, 0, t1 + 2); VMCNT(3); }
        BARRIER(); __builtin_amdgcn_sched_barrier(0);
        mmQ1(4);
        BARRIER();
    }

    #pragma unroll
    for (int i = 0; i < 8; ++i)
        #pragma unroll
        for (int j = 0; j < 3; ++j)
            #pragma unroll
            for (int r = 0; r < 4; ++r) {
                long row = baseM + wm * 128 + i * 16 + quad * 4 + r;
                long col = baseN + wn * 48 + j * 16 + l16;
                C[row * (long)N + col] = (bf16)acc[i][j][r];
            }
}

// ---------------------------------------------------------------------------
// gemm_db: NT GEMM 128x128, double-buffered 2-phase, split-K via blockIdx.z.
// fp32 partials [z][M][N]. (o-proj; proven.)
// ---------------------------------------------------------------------------
__global__ __launch_bounds__(256) void gemm_db(
    const bf16* __restrict__ A, const bf16* __restrict__ B,
    float* __restrict__ Cp, int N, int Kd, int lda, int ldb)
{
    __shared__ bf16 As[2][128 * 32];
    __shared__ bf16 Bs[2][128 * 32];

    const int tid  = threadIdx.x;
    const int wave = tid >> 6, lane = tid & 63;
    const int quad = lane >> 4, l16 = lane & 15;
    const int wm = (wave & 1) * 64, wn = (wave >> 1) * 64;
    const long baseM = (long)blockIdx.x * 128;
    const long baseN = (long)blockIdx.y * 128;
    const long koff  = (long)blockIdx.z * Kd;

    const int  srow = wave * 16 + (lane >> 2);
    const int  scol = (lane & 3) * 8;
    const long aoff0 = (baseM + srow) * (long)lda + koff + scol;
    const long aoff1 = (baseM + 64 + srow) * (long)lda + koff + scol;
    const long boff0 = (baseN + srow) * (long)ldb + koff + scol;
    const long boff1 = (baseN + 64 + srow) * (long)ldb + koff + scol;
    const int  lds0 = wave * 512;
    const int  lds1 = 2048 + wave * 512;

    auto stage = [&](int p, int k0) {
        __builtin_amdgcn_global_load_lds(GLOBAL_AS(A + aoff0 + k0), LDS_AS(As[p] + lds0), 16, 0, 0);
        __builtin_amdgcn_global_load_lds(GLOBAL_AS(A + aoff1 + k0), LDS_AS(As[p] + lds1), 16, 0, 0);
        __builtin_amdgcn_global_load_lds(GLOBAL_AS(B + boff0 + k0), LDS_AS(Bs[p] + lds0), 16, 0, 0);
        __builtin_amdgcn_global_load_lds(GLOBAL_AS(B + boff1 + k0), LDS_AS(Bs[p] + lds1), 16, 0, 0);
    };

    floatx4 acc[4][4] = {};

    stage(0, 0);
    asm volatile("s_waitcnt vmcnt(0)" ::: "memory");
    __builtin_amdgcn_s_barrier();

    int cur = 0;
    for (int k0 = 0; k0 < Kd; k0 += 32) {
        if (k0 + 32 < Kd) stage(cur ^ 1, k0 + 32);   // prefetch next tile
        __builtin_amdgcn_sched_barrier(0);           // pin load issue before compute

        bf16x8 af[4], bfr[4];
        #pragma unroll
        for (int i = 0; i < 4; ++i)
            af[i] = *(const bf16x8*)(As[cur] + (wm + i * 16 + l16) * 32 + quad * 8);
        #pragma unroll
        for (int j = 0; j < 4; ++j)
            bfr[j] = *(const bf16x8*)(Bs[cur] + (wn + j * 16 + l16) * 32 + quad * 8);

        #pragma unroll
        for (int i = 0; i < 4; ++i)
            #pragma unroll
            for (int j = 0; j < 4; ++j)
                acc[i][j] = __builtin_amdgcn_mfma_f32_16x16x32_bf16(af[i], bfr[j], acc[i][j], 0, 0, 0);

        asm volatile("s_waitcnt vmcnt(0)" ::: "memory");  // next tile landed
        __builtin_amdgcn_s_barrier();                     // all readers of cur done
        cur ^= 1;
    }

    const long Mrows = (long)gridDim.x * 128;
    float* C = Cp + (long)blockIdx.z * Mrows * N;
    #pragma unroll
    for (int i = 0; i < 4; ++i)
        #pragma unroll
        for (int j = 0; j < 4; ++j)
            #pragma unroll
            for (int r = 0; r < 4; ++r) {
                long row = baseM + wm + i * 16 + quad * 4 + r;
                long col = baseN + wn + j * 16 + l16;
                C[row * (long)N + col] = acc[i][j][r];
            }
}

// ---------------------------------------------------------------------------
// reduce2: out = P0 + P1, cast per flag. HBM-bound.
// ---------------------------------------------------------------------------
__global__ __launch_bounds__(256) void reduce2(
    const float* __restrict__ P0, const float* __restrict__ P1,
    void* __restrict__ out, const int* flagp)
{
    long i = ((long)blockIdx.x * 256 + threadIdx.x) * 4;
    floatx4 a = *(const floatx4*)(P0 + i);
    floatx4 b = *(const floatx4*)(P1 + i);
    floatx4 s = a + b;
    if (*flagp) {
        bf16x4 o;
        #pragma unroll
        for (int r = 0; r < 4; ++r) o[r] = (bf16)s[r];
        *(bf16x4*)((bf16*)out + i) = o;
    } else {
        *(floatx4*)((float*)out + i) = s;
    }
}

// ---------------------------------------------------------------------------
// In-place RMSNorm + RoPE on q/k sections of qkv[t][6144].
// ---------------------------------------------------------------------------
__global__ __launch_bounds__(256) void qkv_post(
    bf16* __restrict__ qkv, const int* __restrict__ positions,
    const bf16* __restrict__ qnw, const bf16* __restrict__ knw)
{
    const int t = blockIdx.x;
    const int tid = threadIdx.x, wave = tid >> 6, lane = tid & 63;
    const float pos = (float)positions[t];

    const float inv = expf(-(float)lane * (float)(9.210340371976184 / 64.0));
    float sn, cs;
    sincosf(pos * inv, &sn, &cs);

    bf16* row = qkv + (long)t * QKV_N;

    for (int u = wave; u < 40; u += 4) {
        bf16* p       = (u < 32) ? row + u * HD : row + Q_SIZE + (u - 32) * HD;
        const bf16* w = (u < 32) ? qnw : knw;
        float x1 = (float)p[lane], x2 = (float)p[lane + 64];
        float ss = x1 * x1 + x2 * x2;
        #pragma unroll
        for (int m = 32; m; m >>= 1) ss += __shfl_xor(ss, m);
        float rr = rsqrtf(ss * (1.f / 128.f) + 1e-6f);
        float y1 = x1 * rr * (float)w[lane];
        float y2 = x2 * rr * (float)w[lane + 64];
        p[lane]      = (bf16)(y1 * cs - y2 * sn);
        p[lane + 64] = (bf16)(y2 * cs + y1 * sn);
    }
}

// ---------------------------------------------------------------------------
// V transpose: vt[kvh][d][t] from qkv[t][5120+kvh*128+d].
// ---------------------------------------------------------------------------
__global__ __launch_bounds__(256) void vtrans(const bf16* __restrict__ qkv,
                                              bf16* __restrict__ vt)
{
    __shared__ bf16 tile[64][136];
    const int t0 = blockIdx.x * 64, kvh = blockIdx.y, tid = threadIdx.x;

    const int rl = tid >> 4, c8 = (tid & 15) * 8;
    const bf16* src = qkv + (long)t0 * QKV_N + 5120 + kvh * HD;
    #pragma unroll
    for (int it = 0; it < 4; ++it) {
        int r = it * 16 + rl;
        *(bf16x8*)(&tile[r][c8]) = *(const bf16x8*)(src + (long)r * QKV_N + c8);
    }
    __syncthreads();

    const int d = tid >> 1, tb = (tid & 1) * 32;
    bf16* dst = vt + ((long)kvh * HD + d) * T_SEQ + t0 + tb;
    #pragma unroll
    for (int it = 0; it < 4; ++it) {
        bf16x8 v;
        #pragma unroll
        for (int j = 0; j < 8; ++j) v[j] = tile[tb + it * 8 + j][d];
        *(bf16x8*)(dst + it * 8) = v;
    }
}

// ---------------------------------------------------------------------------
// attn5: unpaired 64-row q-tiles, grid (head, 32) with iq = 31 - blockIdx.y
// (LPT). 1024 blocks; LDS 48KB -> 3 blocks/CU. Counted vmcnt(4) mid-iter
// keeps the K[t+1] prefetch in flight. P fully in-register via sigma'd K
// staging + v_cvt_pk_bf16_f32 + permlane32_swap.
// ---------------------------------------------------------------------------
__global__ __launch_bounds__(256, 3) void attn5(bf16* qkv, const bf16* __restrict__ vt)
{
    __shared__ bf16 Ks[2][64 * 128];   // [kt-row][d], 16B chunk c at c^(row&15), rows sigma'd
    __shared__ bf16 Vs[128 * 64];      // [d][kt-row], 16B chunk c at c^(d&7), single buffer

    const int tid  = threadIdx.x, wave = tid >> 6, lane = tid & 63;
    const int quad = lane >> 4, l16 = lane & 15;
    const int h = blockIdx.x, kvh = h >> 2;
    const int iq = 31 - blockIdx.y;    // tile index, longest first (LPT)
    const int q0 = iq * 64;

    const float C1 = 0.12753236f;      // 128^-0.5 * log2(e)
    const float C2 = 17.312340f;       // 12 * log2(e)

    bf16x8 qf[4];
    {
        const bf16* qa = qkv + (long)(q0 + wave * 16 + l16) * QKV_N + h * HD + quad * 8;
        #pragma unroll
        for (int ks = 0; ks < 4; ++ks) qf[ks] = *(const bf16x8*)(qa + ks * 32);
    }

    floatx4 oacc[8] = {};
    float ls = 0.f;

    const int krl = lane >> 4, kc = lane & 15;
    const int vrl = lane >> 3, vc = lane & 7;
    const int kswz = (kc ^ (wave * 4 + krl)) * 8;
    const int vswz = (vc ^ (vrl & 7)) * 8;
    const int wsig = ((wave & 1) << 1) | (wave >> 1);           // sigma(wave): 1<->2
    const int sq4  = (((quad & 1) << 1) | (quad >> 1)) << 2;    // sigma(quad)*4

    const bf16* kg0 = qkv + Q_SIZE + kvh * HD;
    const bf16* vg0 = vt + (long)kvh * HD * T_SEQ;

    auto stageK = [&](int p, int kt) {
        const bf16* kg = kg0 + (long)(kt * 64) * QKV_N;
        #pragma unroll
        for (int it = 0; it < 4; ++it) {
            const int rK = it * 16 + wsig * 4 + krl;
            __builtin_amdgcn_global_load_lds(GLOBAL_AS(kg + (long)rK * QKV_N + kswz),
                                             LDS_AS(&Ks[p][it * 2048 + wave * 512]), 16, 0, 0);
        }
    };
    auto stageV = [&](int kt) {
        const bf16* vg = vg0 + kt * 64;
        #pragma unroll
        for (int it = 0; it < 4; ++it) {
            const int dV = it * 32 + wave * 8 + vrl;
            __builtin_amdgcn_global_load_lds(GLOBAL_AS(vg + (long)dV * T_SEQ + vswz),
                                             LDS_AS(&Vs[it * 2048 + wave * 512]), 16, 0, 0);
        }
    };

    stageK(0, 0);

    const int qg = q0 + wave * 16 + l16;

    for (int kt = 0; kt <= iq; ++kt) {
        const int p = kt & 1;
        __syncthreads();                   // K[p] landed (vmcnt0); all Vs readers done
        stageV(kt);                        // V first (counted-wait relies on FIFO retire)
        if (kt < iq) stageK(p ^ 1, kt + 1);

        const int k0 = kt * 64;

        floatx4 sT[4] = {};
        #pragma unroll
        for (int j2 = 0; j2 < 4; ++j2)
            #pragma unroll
            for (int ks = 0; ks < 4; ++ks) {
                bf16x8 kf = *(const bf16x8*)(&Ks[p][(j2 * 16 + l16) * 128 + (((ks * 4 + quad) ^ l16) * 8)]);
                sT[j2] = __builtin_amdgcn_mfma_f32_16x16x32_bf16(kf, qf[ks], sT[j2], 0, 0, 0);
            }

        const bool diag = (kt == iq);
        unsigned lov[4], hiv[4];
        #pragma unroll
        for (int j2 = 0; j2 < 4; ++j2) {
            float ev[4];
            #pragma unroll
            for (int r = 0; r < 4; ++r) {
                float x = __builtin_amdgcn_exp2f(sT[j2][r] * C1 - C2);
                if (diag && (k0 + j2 * 16 + sq4 + r > qg)) x = 0.f;
                ls += x;
                ev[r] = x;
            }
            asm("v_cvt_pk_bf16_f32 %0, %1, %2" : "=v"(lov[j2]) : "v"(ev[0]), "v"(ev[1]));
            asm("v_cvt_pk_bf16_f32 %0, %1, %2" : "=v"(hiv[j2]) : "v"(ev[2]), "v"(ev[3]));
        }

        bf16x8 pa[2];
        #pragma unroll
        for (int ks2 = 0; ks2 < 2; ++ks2) {
            auto wl = __builtin_amdgcn_permlane32_swap(lov[2 * ks2], lov[2 * ks2 + 1], false, false);
            auto wh = __builtin_amdgcn_permlane32_swap(hiv[2 * ks2], hiv[2 * ks2 + 1], false, false);
            union { unsigned w[4]; bf16x8 v; } u;
            u.w[0] = wl[0]; u.w[1] = wh[0]; u.w[2] = wl[1]; u.w[3] = wh[1];
            pa[ks2] = u.v;
        }

        if (kt < iq) asm volatile("s_waitcnt vmcnt(4)" ::: "memory");
        else         asm volatile("s_waitcnt vmcnt(0)" ::: "memory");
        __builtin_amdgcn_s_barrier();
        __builtin_amdgcn_sched_barrier(0);

        #pragma unroll
        for (int ks2 = 0; ks2 < 2; ++ks2)
            #pragma unroll
            for (int vj = 0; vj < 8; ++vj) {
                const int d = vj * 16 + l16;
                bf16x8 vb = *(const bf16x8*)(&Vs[d * 64 + (((ks2 * 4 + quad) ^ (d & 7)) * 8)]);
                oacc[vj] = __builtin_amdgcn_mfma_f32_16x16x32_bf16(pa[ks2], vb, oacc[vj], 0, 0, 0);
            }
    }

    ls += __shfl_xor(ls, 16); ls += __shfl_xor(ls, 32);
    float rinv[4];
    #pragma unroll
    for (int r = 0; r < 4; ++r) rinv[r] = 1.f / __shfl(ls, quad * 4 + r);

    #pragma unroll
    for (int vj = 0; vj < 8; ++vj)
        #pragma unroll
        for (int r = 0; r < 4; ++r) {
            const long row = q0 + wave * 16 + quad * 4 + r;
            qkv[row * (long)QKV_N + h * HD + vj * 16 + l16] = (bf16)(oacc[vj][r] * rinv[r]);
        }
}

// ---------------------------------------------------------------------------
extern "C" void kernel_launch(void* const* d_in, const int* in_sizes, int n_in,
                              void* d_out, int out_size, void* d_ws, size_t ws_size,
                              hipStream_t stream)
{
    const int* positions = (const int*)d_in[0];

    char* ws = (char*)d_ws;
    bf16* qkv  = (bf16*)(ws);              // [2048][6144]  25165824 B
    bf16* hb   = (bf16*)(ws + 25165824);   // [2048][2048]   8388608 B (dead after gemm1)
    bf16* vt   = hb;                       // [8][128][2048] 4194304 B (aliases hb)
    // o-proj split-K partials: live only after attn5 (hb/vt and wqb both dead)
    float* P0  = (float*)(ws + 25165824);  // [2048][2048] fp32 16777216 B
    float* P1  = (float*)(ws + 41943040);  // [2048][2048] fp32 16777216 B (ends at wob)
    bf16* wqb  = (bf16*)(ws + 33554432);   // [6144][2048]  25165824 B
    bf16* wob  = (bf16*)(ws + 58720256);   // [2048][4096]  16777216 B
    bf16* qnb  = (bf16*)(ws + 75497472);
    bf16* knb  = (bf16*)(ws + 75497728);
    int*  flag = (int*) (ws + 75497984);

    detect_dtype<<<dim3(1), dim3(64), 0, stream>>>((const unsigned short*)d_in[2], flag);
    convert_all<<<dim3(12289), dim3(256), 0, stream>>>(
        d_in[1], d_in[2], d_in[3], d_in[4], d_in[5],
        hb, wqb, wob, qnb, knb, flag);

    // QKV proj: 256x192 8-phase dbuf tiles, grid (32, 8) = 256 blocks (full chip).
    gemm8p<<<dim3(QKV_N / 192, T_SEQ / 256), dim3(512), 0, stream>>>(
        hb, wqb, qkv, QKV_N, HIDDEN, HIDDEN, HIDDEN);
    vtrans<<<dim3(T_SEQ / 64, NUM_KV), dim3(256), 0, stream>>>(qkv, vt);
    qkv_post<<<dim3(T_SEQ), dim3(256), 0, stream>>>(qkv, positions, qnb, knb);
    attn5<<<dim3(NUM_H, 32), dim3(256), 0, stream>>>(qkv, vt);
    // o-proj: split-K=2, 128x128 dbuf tiles, fp32 partials, then reduce.
    gemm_db<<<dim3(T_SEQ / 128, HIDDEN / 128, 2), dim3(256), 0, stream>>>(
        qkv, wob, P0, HIDDEN, Q_SIZE / 2, QKV_N, Q_SIZE);
    reduce2<<<dim3(4096), dim3(256), 0, stream>>>(P0, P1, d_out, flag);
}

// Round 6
// 308.166 us; speedup vs baseline: 1.2841x; 1.0350x over previous
//
#include <hip/hip_runtime.h>
#include <hip/hip_bf16.h>

#define T_SEQ   2048
#define HIDDEN  2048
#define NUM_H   32
#define NUM_KV  8
#define HD      128
#define Q_SIZE  4096
#define QKV_N   6144

typedef __bf16 bf16;
typedef __bf16 bf16x8 __attribute__((ext_vector_type(8)));
typedef __bf16 bf16x4 __attribute__((ext_vector_type(4)));
typedef float  floatx4 __attribute__((ext_vector_type(4)));

#define GLOBAL_AS(p) ((const __attribute__((address_space(1))) void*)(p))
#define LDS_AS(p)    ((__attribute__((address_space(3))) void*)(p))

// memory-clobber-wrapped barrier: blocks compiler memory reordering across it
#define BARRIER() do { asm volatile("" ::: "memory"); \
                       __builtin_amdgcn_s_barrier();  \
                       asm volatile("" ::: "memory"); } while (0)
#define VMCNT(n) asm volatile("s_waitcnt vmcnt(" #n ")" ::: "memory")

// ---------------------------------------------------------------------------
// Dtype detection (fp32 vs bf16 inputs). flag=1 => bf16.
// ---------------------------------------------------------------------------
__global__ void detect_dtype(const unsigned short* __restrict__ wq, int* flagp)
{
    const int lane = threadIdx.x;   // 64 threads
    int cnt = 0;
    for (int i = lane; i < 512; i += 64) {
        int ef = (wq[i] >> 7) & 0xFF;
        if (ef >= 90 && ef <= 130) cnt++;
    }
    #pragma unroll
    for (int m = 32; m; m >>= 1) cnt += __shfl_xor(cnt, m);
    if (lane == 0) *flagp = (cnt >= 430) ? 1 : 0;
}

// ---------------------------------------------------------------------------
// Canonicalize all float inputs into bf16 workspace copies.
// ---------------------------------------------------------------------------
__global__ __launch_bounds__(256) void convert_all(
    const void* __restrict__ h, const void* __restrict__ wq,
    const void* __restrict__ wo_, const void* __restrict__ qn,
    const void* __restrict__ kn,
    bf16* __restrict__ hb, bf16* __restrict__ wqb, bf16* __restrict__ wob,
    bf16* __restrict__ qnb, bf16* __restrict__ knb, const int* flagp)
{
    long e = ((long)blockIdx.x * 256 + threadIdx.x) * 8;
    const void* src; bf16* dst; long off;
    if      (e < 4194304)  { src = h;   dst = hb;  off = e; }
    else if (e < 16777216) { src = wq;  dst = wqb; off = e - 4194304; }
    else if (e < 25165824) { src = wo_; dst = wob; off = e - 16777216; }
    else if (e < 25165952) { src = qn;  dst = qnb; off = e - 25165824; }
    else if (e < 25166080) { src = kn;  dst = knb; off = e - 25165952; }
    else return;

    if (*flagp) {
        *(bf16x8*)(dst + off) = *(const bf16x8*)((const bf16*)src + off);
    } else {
        const float* f = (const float*)src + off;
        bf16x8 v;
        #pragma unroll
        for (int i = 0; i < 8; ++i) v[i] = (bf16)f[i];
        *(bf16x8*)(dst + off) = v;
    }
}

// ---------------------------------------------------------------------------
// gemm8p: NT GEMM, 256(M) x 192(N) tile, BK=64, 8 waves, 8-phase counted
// vmcnt. FROZEN this round (per-phase latency-bound at 1 block/CU; see R5
// post-mortem). Grid (N/192, M/256) = 256 blocks.
// ---------------------------------------------------------------------------
__global__ __launch_bounds__(512, 2) void gemm8p(
    const bf16* __restrict__ A, const bf16* __restrict__ B,
    bf16* __restrict__ C, int N, int K, int lda, int ldb)
{
    __shared__ bf16 As[2][2][128 * 64];   // [dbuf][Mhalf][row*64+col], swizzled
    __shared__ bf16 Bs[2][192 * 64];      // [dbuf][row*64+col], row = C-col idx

    const int tid  = threadIdx.x;
    const int wave = tid >> 6, lane = tid & 63;
    const int quad = lane >> 4, l16 = lane & 15;
    const int wm = wave >> 2;            // M half this wave computes/reads
    const int wn = wave & 3;             // N quarter (48 cols)
    const long baseN = (long)blockIdx.x * 192;
    const long baseM = (long)blockIdx.y * 256;

    const int sr  = tid >> 3;
    const int sgc = ((tid & 7) ^ (sr & 7)) * 8;

    auto stagePA = [&](int p, int g, int t) {
        const long kc = (long)t * 64;
        const bf16* src = A + (baseM + g * 64 + sr) * (long)lda + kc + sgc;
        __builtin_amdgcn_global_load_lds(GLOBAL_AS(src),
            LDS_AS(&As[p][0][g * 4096 + wave * 512]), 16, 0, 0);
        __builtin_amdgcn_global_load_lds(GLOBAL_AS(src + 128 * (long)lda),
            LDS_AS(&As[p][1][g * 4096 + wave * 512]), 16, 0, 0);
    };
    auto stagePBu = [&](int p, int u, int t) {
        const long kc = (long)t * 64;
        const bf16* src = B + (baseN + u * 64 + sr) * (long)ldb + kc + sgc;
        __builtin_amdgcn_global_load_lds(GLOBAL_AS(src),
            LDS_AS(&Bs[p][u * 4096 + wave * 512]), 16, 0, 0);
    };

    floatx4 acc[8][3] = {};   // [mf 0..7][nf 0..2]
    bf16x8 af[4][2], bf01[2][2], bf2[2];

    auto rdAf = [&](int p, int g) {
        #pragma unroll
        for (int mf = 0; mf < 4; ++mf)
            #pragma unroll
            for (int ks = 0; ks < 2; ++ks) {
                const int r = g * 64 + mf * 16 + l16;
                af[mf][ks] = *(const bf16x8*)(&As[p][wm][r * 64 + (((ks * 4 + quad) ^ (r & 7)) * 8)]);
            }
    };
    auto rdB01 = [&](int p) {
        #pragma unroll
        for (int nf = 0; nf < 2; ++nf)
            #pragma unroll
            for (int ks = 0; ks < 2; ++ks) {
                const int r = wn * 48 + nf * 16 + l16;
                bf01[nf][ks] = *(const bf16x8*)(&Bs[p][r * 64 + (((ks * 4 + quad) ^ (r & 7)) * 8)]);
            }
    };
    auto rdB2 = [&](int p) {
        #pragma unroll
        for (int ks = 0; ks < 2; ++ks) {
            const int r = wn * 48 + 32 + l16;
            bf2[ks] = *(const bf16x8*)(&Bs[p][r * 64 + (((ks * 4 + quad) ^ (r & 7)) * 8)]);
        }
    };
    auto mmQ2 = [&](int mo) {
        __builtin_amdgcn_s_setprio(1);
        #pragma unroll
        for (int mf = 0; mf < 4; ++mf)
            #pragma unroll
            for (int nf = 0; nf < 2; ++nf)
                #pragma unroll
                for (int ks = 0; ks < 2; ++ks)
                    acc[mo + mf][nf] = __builtin_amdgcn_mfma_f32_16x16x32_bf16(
                        af[mf][ks], bf01[nf][ks], acc[mo + mf][nf], 0, 0, 0);
        __builtin_amdgcn_s_setprio(0);
    };
    auto mmQ1 = [&](int mo) {
        __builtin_amdgcn_s_setprio(1);
        #pragma unroll
        for (int mf = 0; mf < 4; ++mf)
            #pragma unroll
            for (int ks = 0; ks < 2; ++ks)
                acc[mo + mf][2] = __builtin_amdgcn_mfma_f32_16x16x32_bf16(
                    af[mf][ks], bf2[ks], acc[mo + mf][2], 0, 0, 0);
        __builtin_amdgcn_s_setprio(0);
    };

    stagePBu(0, 0, 0); stagePBu(0, 1, 0); stagePBu(0, 2, 0);
    stagePA(0, 0, 0);  stagePA(0, 1, 0);
    stagePBu(1, 0, 1);
    VMCNT(1);
    BARRIER();

    const int NT2 = K / 128;   // iterations of 2 K-tiles
    for (int j = 0; j < NT2; ++j) {
        const int t1 = 2 * j + 1;
        const bool more = (j + 1 < NT2);

        rdAf(0, 0); rdB01(0);
        stagePBu(1, 1, t1); stagePBu(1, 2, t1);
        BARRIER(); __builtin_amdgcn_sched_barrier(0);
        mmQ2(0);
        BARRIER();

        rdB2(0);
        stagePA(1, 0, t1);
        VMCNT(5);
        BARRIER(); __builtin_amdgcn_sched_barrier(0);
        mmQ1(0);
        BARRIER();

        rdAf(0, 1);
        stagePA(1, 1, t1);
        BARRIER(); __builtin_amdgcn_sched_barrier(0);
        mmQ2(4);
        BARRIER();

        if (more) { stagePBu(0, 0, t1 + 1); VMCNT(3); } else { VMCNT(2); }
        BARRIER(); __builtin_amdgcn_sched_barrier(0);
        mmQ1(4);
        BARRIER();

        rdAf(1, 0); rdB01(1);
        if (more) { stagePBu(0, 1, t1 + 1); stagePBu(0, 2, t1 + 1); }
        BARRIER(); __builtin_amdgcn_sched_barrier(0);
        mmQ2(0);
        BARRIER();

        rdB2(1);
        if (more) { stagePA(0, 0, t1 + 1); VMCNT(5); } else { VMCNT(0); }
        BARRIER(); __builtin_amdgcn_sched_barrier(0);
        mmQ1(0);
        BARRIER();

        rdAf(1, 1);
        if (more) stagePA(0, 1, t1 + 1);
        BARRIER(); __builtin_amdgcn_sched_barrier(0);
        mmQ2(4);
        BARRIER();

        if (more) { stagePBu(1, 0, t1 + 2); VMCNT(3); }
        BARRIER(); __builtin_amdgcn_sched_barrier(0);
        mmQ1(4);
        BARRIER();
    }

    #pragma unroll
    for (int i = 0; i < 8; ++i)
        #pragma unroll
        for (int j = 0; j < 3; ++j)
            #pragma unroll
            for (int r = 0; r < 4; ++r) {
                long row = baseM + wm * 128 + i * 16 + quad * 4 + r;
                long col = baseN + wn * 48 + j * 16 + l16;
                C[row * (long)N + col] = (bf16)acc[i][j][r];
            }
}

// ---------------------------------------------------------------------------
// gemm_db64: NT GEMM 128x128, 4 waves (2Mx2N, per-wave 64x64), BK=64,
// double-buffered with NEVER-DRAIN counted vmcnt (T3+T4 at 2 blocks/CU —
// the regime where co-resident blocks hide barrier overhead, m97-style).
// Per K-tile: { stage(buf^1, t+1) [8 loads] -> VMCNT(8) -> BARRIER ->
// 16 ds_read_b128 -> 32 MFMA (setprio) -> BARRIER }. WAR safe: trailing
// barrier precedes any re-stage of that buffer. LDS 64KB -> 2 blocks/CU.
// Chunk-XOR swizzle identical to gemm8p (0 conflicts measured there).
// Split-K via blockIdx.z -> fp32 partials [z][M][N].
// ---------------------------------------------------------------------------
__global__ __launch_bounds__(256, 2) void gemm_db64(
    const bf16* __restrict__ A, const bf16* __restrict__ B,
    float* __restrict__ Cp, int N, int Kd, int lda, int ldb)
{
    __shared__ bf16 As[2][128 * 64];
    __shared__ bf16 Bs[2][128 * 64];

    const int tid  = threadIdx.x;
    const int wave = tid >> 6, lane = tid & 63;
    const int quad = lane >> 4, l16 = lane & 15;
    const int wm = (wave & 1) * 64, wn = (wave >> 1) * 64;
    const long baseM = (long)blockIdx.x * 128;
    const long baseN = (long)blockIdx.y * 128;
    const long koff  = (long)blockIdx.z * Kd;

    // staging: 4 calls/operand, call u covers rows u*32..+31 (256thr x 16B)
    const int sr  = tid >> 3;                      // row within 32-row unit
    const int sgc = ((tid & 7) ^ (sr & 7)) * 8;    // pre-swizzled global chunk

    auto stage = [&](int p, int t) {
        const long kc = koff + (long)t * 64;
        #pragma unroll
        for (int u = 0; u < 4; ++u) {
            const bf16* sa = A + (baseM + u * 32 + sr) * (long)lda + kc + sgc;
            __builtin_amdgcn_global_load_lds(GLOBAL_AS(sa),
                LDS_AS(&As[p][u * 2048 + wave * 512]), 16, 0, 0);
        }
        #pragma unroll
        for (int u = 0; u < 4; ++u) {
            const bf16* sb = B + (baseN + u * 32 + sr) * (long)ldb + kc + sgc;
            __builtin_amdgcn_global_load_lds(GLOBAL_AS(sb),
                LDS_AS(&Bs[p][u * 2048 + wave * 512]), 16, 0, 0);
        }
    };

    floatx4 acc[4][4] = {};

    stage(0, 0);

    const int NT = Kd / 64;
    int cur = 0;
    for (int t = 0; t < NT; ++t) {
        if (t + 1 < NT) { stage(cur ^ 1, t + 1); VMCNT(8); }   // tile t landed
        else            { VMCNT(0); }
        BARRIER();                         // all waves' tile-t loads visible

        bf16x8 af[4][2], bfr[4][2];
        #pragma unroll
        for (int i = 0; i < 4; ++i)
            #pragma unroll
            for (int ks = 0; ks < 2; ++ks) {
                const int r = wm + i * 16 + l16;
                af[i][ks] = *(const bf16x8*)(&As[cur][r * 64 + (((ks * 4 + quad) ^ (r & 7)) * 8)]);
            }
        #pragma unroll
        for (int j = 0; j < 4; ++j)
            #pragma unroll
            for (int ks = 0; ks < 2; ++ks) {
                const int r = wn + j * 16 + l16;
                bfr[j][ks] = *(const bf16x8*)(&Bs[cur][r * 64 + (((ks * 4 + quad) ^ (r & 7)) * 8)]);
            }

        __builtin_amdgcn_s_setprio(1);
        #pragma unroll
        for (int i = 0; i < 4; ++i)
            #pragma unroll
            for (int j = 0; j < 4; ++j)
                #pragma unroll
                for (int ks = 0; ks < 2; ++ks)
                    acc[i][j] = __builtin_amdgcn_mfma_f32_16x16x32_bf16(
                        af[i][ks], bfr[j][ks], acc[i][j], 0, 0, 0);
        __builtin_amdgcn_s_setprio(0);

        BARRIER();                         // reads of buf cur done -> may re-stage
        cur ^= 1;
    }

    const long Mrows = (long)gridDim.x * 128;
    float* C = Cp + (long)blockIdx.z * Mrows * N;
    #pragma unroll
    for (int i = 0; i < 4; ++i)
        #pragma unroll
        for (int j = 0; j < 4; ++j)
            #pragma unroll
            for (int r = 0; r < 4; ++r) {
                long row = baseM + wm + i * 16 + quad * 4 + r;
                long col = baseN + wn + j * 16 + l16;
                C[row * (long)N + col] = acc[i][j][r];
            }
}

// ---------------------------------------------------------------------------
// reduce2: out = P0 + P1, cast per flag. HBM-bound.
// ---------------------------------------------------------------------------
__global__ __launch_bounds__(256) void reduce2(
    const float* __restrict__ P0, const float* __restrict__ P1,
    void* __restrict__ out, const int* flagp)
{
    long i = ((long)blockIdx.x * 256 + threadIdx.x) * 4;
    floatx4 a = *(const floatx4*)(P0 + i);
    floatx4 b = *(const floatx4*)(P1 + i);
    floatx4 s = a + b;
    if (*flagp) {
        bf16x4 o;
        #pragma unroll
        for (int r = 0; r < 4; ++r) o[r] = (bf16)s[r];
        *(bf16x4*)((bf16*)out + i) = o;
    } else {
        *(floatx4*)((float*)out + i) = s;
    }
}

// ---------------------------------------------------------------------------
// In-place RMSNorm + RoPE on q/k sections of qkv[t][6144].
// ---------------------------------------------------------------------------
__global__ __launch_bounds__(256) void qkv_post(
    bf16* __restrict__ qkv, const int* __restrict__ positions,
    const bf16* __restrict__ qnw, const bf16* __restrict__ knw)
{
    const int t = blockIdx.x;
    const int tid = threadIdx.x, wave = tid >> 6, lane = tid & 63;
    const float pos = (float)positions[t];

    const float inv = expf(-(float)lane * (float)(9.210340371976184 / 64.0));
    float sn, cs;
    sincosf(pos * inv, &sn, &cs);

    bf16* row = qkv + (long)t * QKV_N;

    for (int u = wave; u < 40; u += 4) {
        bf16* p       = (u < 32) ? row + u * HD : row + Q_SIZE + (u - 32) * HD;
        const bf16* w = (u < 32) ? qnw : knw;
        float x1 = (float)p[lane], x2 = (float)p[lane + 64];
        float ss = x1 * x1 + x2 * x2;
        #pragma unroll
        for (int m = 32; m; m >>= 1) ss += __shfl_xor(ss, m);
        float rr = rsqrtf(ss * (1.f / 128.f) + 1e-6f);
        float y1 = x1 * rr * (float)w[lane];
        float y2 = x2 * rr * (float)w[lane + 64];
        p[lane]      = (bf16)(y1 * cs - y2 * sn);
        p[lane + 64] = (bf16)(y2 * cs + y1 * sn);
    }
}

// ---------------------------------------------------------------------------
// V transpose: vt[kvh][d][t] from qkv[t][5120+kvh*128+d].
// ---------------------------------------------------------------------------
__global__ __launch_bounds__(256) void vtrans(const bf16* __restrict__ qkv,
                                              bf16* __restrict__ vt)
{
    __shared__ bf16 tile[64][136];
    const int t0 = blockIdx.x * 64, kvh = blockIdx.y, tid = threadIdx.x;

    const int rl = tid >> 4, c8 = (tid & 15) * 8;
    const bf16* src = qkv + (long)t0 * QKV_N + 5120 + kvh * HD;
    #pragma unroll
    for (int it = 0; it < 4; ++it) {
        int r = it * 16 + rl;
        *(bf16x8*)(&tile[r][c8]) = *(const bf16x8*)(src + (long)r * QKV_N + c8);
    }
    __syncthreads();

    const int d = tid >> 1, tb = (tid & 1) * 32;
    bf16* dst = vt + ((long)kvh * HD + d) * T_SEQ + t0 + tb;
    #pragma unroll
    for (int it = 0; it < 4; ++it) {
        bf16x8 v;
        #pragma unroll
        for (int j = 0; j < 8; ++j) v[j] = tile[tb + it * 8 + j][d];
        *(bf16x8*)(dst + it * 8) = v;
    }
}

// ---------------------------------------------------------------------------
// attn5: unpaired 64-row q-tiles, grid (head, 32) with iq = 31 - blockIdx.y
// (LPT). 1024 blocks; LDS 48KB -> 3 blocks/CU. Counted vmcnt(4) mid-iter
// keeps the K[t+1] prefetch in flight. P fully in-register via sigma'd K
// staging + v_cvt_pk_bf16_f32 + permlane32_swap.
// ---------------------------------------------------------------------------
__global__ __launch_bounds__(256, 3) void attn5(bf16* qkv, const bf16* __restrict__ vt)
{
    __shared__ bf16 Ks[2][64 * 128];   // [kt-row][d], 16B chunk c at c^(row&15), rows sigma'd
    __shared__ bf16 Vs[128 * 64];      // [d][kt-row], 16B chunk c at c^(d&7), single buffer

    const int tid  = threadIdx.x, wave = tid >> 6, lane = tid & 63;
    const int quad = lane >> 4, l16 = lane & 15;
    const int h = blockIdx.x, kvh = h >> 2;
    const int iq = 31 - blockIdx.y;    // tile index, longest first (LPT)
    const int q0 = iq * 64;

    const float C1 = 0.12753236f;      // 128^-0.5 * log2(e)
    const float C2 = 17.312340f;       // 12 * log2(e)

    bf16x8 qf[4];
    {
        const bf16* qa = qkv + (long)(q0 + wave * 16 + l16) * QKV_N + h * HD + quad * 8;
        #pragma unroll
        for (int ks = 0; ks < 4; ++ks) qf[ks] = *(const bf16x8*)(qa + ks * 32);
    }

    floatx4 oacc[8] = {};
    float ls = 0.f;

    const int krl = lane >> 4, kc = lane & 15;
    const int vrl = lane >> 3, vc = lane & 7;
    const int kswz = (kc ^ (wave * 4 + krl)) * 8;
    const int vswz = (vc ^ (vrl & 7)) * 8;
    const int wsig = ((wave & 1) << 1) | (wave >> 1);           // sigma(wave): 1<->2
    const int sq4  = (((quad & 1) << 1) | (quad >> 1)) << 2;    // sigma(quad)*4

    const bf16* kg0 = qkv + Q_SIZE + kvh * HD;
    const bf16* vg0 = vt + (long)kvh * HD * T_SEQ;

    auto stageK = [&](int p, int kt) {
        const bf16* kg = kg0 + (long)(kt * 64) * QKV_N;
        #pragma unroll
        for (int it = 0; it < 4; ++it) {
            const int rK = it * 16 + wsig * 4 + krl;
            __builtin_amdgcn_global_load_lds(GLOBAL_AS(kg + (long)rK * QKV_N + kswz),
                                             LDS_AS(&Ks[p][it * 2048 + wave * 512]), 16, 0, 0);
        }
    };
    auto stageV = [&](int kt) {
        const bf16* vg = vg0 + kt * 64;
        #pragma unroll
        for (int it = 0; it < 4; ++it) {
            const int dV = it * 32 + wave * 8 + vrl;
            __builtin_amdgcn_global_load_lds(GLOBAL_AS(vg + (long)dV * T_SEQ + vswz),
                                             LDS_AS(&Vs[it * 2048 + wave * 512]), 16, 0, 0);
        }
    };

    stageK(0, 0);

    const int qg = q0 + wave * 16 + l16;

    for (int kt = 0; kt <= iq; ++kt) {
        const int p = kt & 1;
        __syncthreads();                   // K[p] landed (vmcnt0); all Vs readers done
        stageV(kt);                        // V first (counted-wait relies on FIFO retire)
        if (kt < iq) stageK(p ^ 1, kt + 1);

        const int k0 = kt * 64;

        floatx4 sT[4] = {};
        #pragma unroll
        for (int j2 = 0; j2 < 4; ++j2)
            #pragma unroll
            for (int ks = 0; ks < 4; ++ks) {
                bf16x8 kf = *(const bf16x8*)(&Ks[p][(j2 * 16 + l16) * 128 + (((ks * 4 + quad) ^ l16) * 8)]);
                sT[j2] = __builtin_amdgcn_mfma_f32_16x16x32_bf16(kf, qf[ks], sT[j2], 0, 0, 0);
            }

        const bool diag = (kt == iq);
        unsigned lov[4], hiv[4];
        #pragma unroll
        for (int j2 = 0; j2 < 4; ++j2) {
            float ev[4];
            #pragma unroll
            for (int r = 0; r < 4; ++r) {
                float x = __builtin_amdgcn_exp2f(sT[j2][r] * C1 - C2);
                if (diag && (k0 + j2 * 16 + sq4 + r > qg)) x = 0.f;
                ls += x;
                ev[r] = x;
            }
            asm("v_cvt_pk_bf16_f32 %0, %1, %2" : "=v"(lov[j2]) : "v"(ev[0]), "v"(ev[1]));
            asm("v_cvt_pk_bf16_f32 %0, %1, %2" : "=v"(hiv[j2]) : "v"(ev[2]), "v"(ev[3]));
        }

        bf16x8 pa[2];
        #pragma unroll
        for (int ks2 = 0; ks2 < 2; ++ks2) {
            auto wl = __builtin_amdgcn_permlane32_swap(lov[2 * ks2], lov[2 * ks2 + 1], false, false);
            auto wh = __builtin_amdgcn_permlane32_swap(hiv[2 * ks2], hiv[2 * ks2 + 1], false, false);
            union { unsigned w[4]; bf16x8 v; } u;
            u.w[0] = wl[0]; u.w[1] = wh[0]; u.w[2] = wl[1]; u.w[3] = wh[1];
            pa[ks2] = u.v;
        }

        if (kt < iq) asm volatile("s_waitcnt vmcnt(4)" ::: "memory");
        else         asm volatile("s_waitcnt vmcnt(0)" ::: "memory");
        __builtin_amdgcn_s_barrier();
        __builtin_amdgcn_sched_barrier(0);

        #pragma unroll
        for (int ks2 = 0; ks2 < 2; ++ks2)
            #pragma unroll
            for (int vj = 0; vj < 8; ++vj) {
                const int d = vj * 16 + l16;
                bf16x8 vb = *(const bf16x8*)(&Vs[d * 64 + (((ks2 * 4 + quad) ^ (d & 7)) * 8)]);
                oacc[vj] = __builtin_amdgcn_mfma_f32_16x16x32_bf16(pa[ks2], vb, oacc[vj], 0, 0, 0);
            }
    }

    ls += __shfl_xor(ls, 16); ls += __shfl_xor(ls, 32);
    float rinv[4];
    #pragma unroll
    for (int r = 0; r < 4; ++r) rinv[r] = 1.f / __shfl(ls, quad * 4 + r);

    #pragma unroll
    for (int vj = 0; vj < 8; ++vj)
        #pragma unroll
        for (int r = 0; r < 4; ++r) {
            const long row = q0 + wave * 16 + quad * 4 + r;
            qkv[row * (long)QKV_N + h * HD + vj * 16 + l16] = (bf16)(oacc[vj][r] * rinv[r]);
        }
}

// ---------------------------------------------------------------------------
extern "C" void kernel_launch(void* const* d_in, const int* in_sizes, int n_in,
                              void* d_out, int out_size, void* d_ws, size_t ws_size,
                              hipStream_t stream)
{
    const int* positions = (const int*)d_in[0];

    char* ws = (char*)d_ws;
    bf16* qkv  = (bf16*)(ws);              // [2048][6144]  25165824 B
    bf16* hb   = (bf16*)(ws + 25165824);   // [2048][2048]   8388608 B (dead after gemm1)
    bf16* vt   = hb;                       // [8][128][2048] 4194304 B (aliases hb)
    // o-proj split-K partials: live only after attn5 (hb/vt and wqb both dead)
    float* P0  = (float*)(ws + 25165824);  // [2048][2048] fp32 16777216 B
    float* P1  = (float*)(ws + 41943040);  // [2048][2048] fp32 16777216 B (ends at wob)
    bf16* wqb  = (bf16*)(ws + 33554432);   // [6144][2048]  25165824 B
    bf16* wob  = (bf16*)(ws + 58720256);   // [2048][4096]  16777216 B
    bf16* qnb  = (bf16*)(ws + 75497472);
    bf16* knb  = (bf16*)(ws + 75497728);
    int*  flag = (int*) (ws + 75497984);

    detect_dtype<<<dim3(1), dim3(64), 0, stream>>>((const unsigned short*)d_in[2], flag);
    convert_all<<<dim3(12289), dim3(256), 0, stream>>>(
        d_in[1], d_in[2], d_in[3], d_in[4], d_in[5],
        hb, wqb, wob, qnb, knb, flag);

    // QKV proj: 256x192 8-phase dbuf tiles, grid (32, 8) = 256 blocks (full chip).
    gemm8p<<<dim3(QKV_N / 192, T_SEQ / 256), dim3(512), 0, stream>>>(
        hb, wqb, qkv, QKV_N, HIDDEN, HIDDEN, HIDDEN);
    vtrans<<<dim3(T_SEQ / 64, NUM_KV), dim3(256), 0, stream>>>(qkv, vt);
    qkv_post<<<dim3(T_SEQ), dim3(256), 0, stream>>>(qkv, positions, qnb, knb);
    attn5<<<dim3(NUM_H, 32), dim3(256), 0, stream>>>(qkv, vt);
    // o-proj: split-K=2, 128x128 BK=64 never-drain dbuf, 512 blocks = 2/CU.
    gemm_db64<<<dim3(T_SEQ / 128, HIDDEN / 128, 2), dim3(256), 0, stream>>>(
        qkv, wob, P0, HIDDEN, Q_SIZE / 2, QKV_N, Q_SIZE);
    reduce2<<<dim3(4096), dim3(256), 0, stream>>>(P0, P1, d_out, flag);
}

// Round 7
// 306.281 us; speedup vs baseline: 1.2920x; 1.0062x over previous
//
#include <hip/hip_runtime.h>
#include <hip/hip_bf16.h>

#define T_SEQ   2048
#define HIDDEN  2048
#define NUM_H   32
#define NUM_KV  8
#define HD      128
#define Q_SIZE  4096
#define QKV_N   6144

typedef __bf16 bf16;
typedef __bf16 bf16x8 __attribute__((ext_vector_type(8)));
typedef __bf16 bf16x4 __attribute__((ext_vector_type(4)));
typedef float  floatx4 __attribute__((ext_vector_type(4)));

#define GLOBAL_AS(p) ((const __attribute__((address_space(1))) void*)(p))
#define LDS_AS(p)    ((__attribute__((address_space(3))) void*)(p))

// memory-clobber-wrapped barrier: blocks compiler memory reordering across it
#define BARRIER() do { asm volatile("" ::: "memory"); \
                       __builtin_amdgcn_s_barrier();  \
                       asm volatile("" ::: "memory"); } while (0)
#define VMCNT(n) asm volatile("s_waitcnt vmcnt(" #n ")" ::: "memory")
#define SCHED()  __builtin_amdgcn_sched_barrier(0)

// ---------------------------------------------------------------------------
// Dtype detection (fp32 vs bf16 inputs). flag=1 => bf16.
// ---------------------------------------------------------------------------
__global__ void detect_dtype(const unsigned short* __restrict__ wq, int* flagp)
{
    const int lane = threadIdx.x;   // 64 threads
    int cnt = 0;
    for (int i = lane; i < 512; i += 64) {
        int ef = (wq[i] >> 7) & 0xFF;
        if (ef >= 90 && ef <= 130) cnt++;
    }
    #pragma unroll
    for (int m = 32; m; m >>= 1) cnt += __shfl_xor(cnt, m);
    if (lane == 0) *flagp = (cnt >= 430) ? 1 : 0;
}

// ---------------------------------------------------------------------------
// Canonicalize all float inputs into bf16 workspace copies.
// ---------------------------------------------------------------------------
__global__ __launch_bounds__(256) void convert_all(
    const void* __restrict__ h, const void* __restrict__ wq,
    const void* __restrict__ wo_, const void* __restrict__ qn,
    const void* __restrict__ kn,
    bf16* __restrict__ hb, bf16* __restrict__ wqb, bf16* __restrict__ wob,
    bf16* __restrict__ qnb, bf16* __restrict__ knb, const int* flagp)
{
    long e = ((long)blockIdx.x * 256 + threadIdx.x) * 8;
    const void* src; bf16* dst; long off;
    if      (e < 4194304)  { src = h;   dst = hb;  off = e; }
    else if (e < 16777216) { src = wq;  dst = wqb; off = e - 4194304; }
    else if (e < 25165824) { src = wo_; dst = wob; off = e - 16777216; }
    else if (e < 25165952) { src = qn;  dst = qnb; off = e - 25165824; }
    else if (e < 25166080) { src = kn;  dst = knb; off = e - 25165952; }
    else return;

    if (*flagp) {
        *(bf16x8*)(dst + off) = *(const bf16x8*)((const bf16*)src + off);
    } else {
        const float* f = (const float*)src + off;
        bf16x8 v;
        #pragma unroll
        for (int i = 0; i < 8; ++i) v[i] = (bf16)f[i];
        *(bf16x8*)(dst + off) = v;
    }
}

// ---------------------------------------------------------------------------
// gemm3p: NT GEMM, 256(M) x 192(N) tile, BK=64, 8 waves (2M x 4N, per-wave
// 128x48), 512 threads, 112 KB LDS, grid (N/192, M/256) = 256 blocks.
// 3 EQUAL phases per K-tile (48 MFMA = 3 x 16; the R4-R6 4-phase version
// averaged 12 MFMA/phase — two half-empty phases paid full phase-wall).
// 5 barriers/tile (was 8). Minimal never-drain ledger, 2 waits/tile:
//   ph1: {rd A-g0 + all B | stage B x3(t+1) -> vmcnt(3) -> bar ->
//         16 MFMA af0xB01 -> bar}   (vmcnt(3) retires t's PA1 for ph2)
//   ph2: {rd A-g1 | stage A-g0(t+1) -> bar -> 16 MFMA (af0+af1)xB2 -> bar}
//   ph3: {stage A-g1(t+1) -> vmcnt(2) -> 16 MFMA af1xB01 -> bar}
//         (vmcnt(2) retires t+1's B + A-g0 = exactly next ph1's reads;
//          t+1's PA1 stays in flight, covered by next ph1's vmcnt(3))
// Reads-after-wait + WAR traced for prologue/steady/tail. Tail drains.
// 16B-chunk XOR swizzle (chunk c at c^(row&7)) on pre-swizzled global
// source + re-applied on ds_read (rule #21); 0 conflicts measured R4-R6.
// ---------------------------------------------------------------------------
__global__ __launch_bounds__(512, 2) void gemm3p(
    const bf16* __restrict__ A, const bf16* __restrict__ B,
    bf16* __restrict__ C, int N, int K, int lda, int ldb)
{
    __shared__ bf16 As[2][2][128 * 64];   // [dbuf][Mhalf][row*64+col], swizzled
    __shared__ bf16 Bs[2][192 * 64];      // [dbuf][row*64+col], row = C-col idx

    const int tid  = threadIdx.x;
    const int wave = tid >> 6, lane = tid & 63;
    const int quad = lane >> 4, l16 = lane & 15;
    const int wm = wave >> 2;            // M half this wave computes/reads
    const int wn = wave & 3;             // N quarter (48 cols)
    const long baseN = (long)blockIdx.x * 192;
    const long baseM = (long)blockIdx.y * 256;

    // staging: unit = 64 rows x 64 cols = 8KB = 1 load/thread.
    const int sr  = tid >> 3;
    const int sgc = ((tid & 7) ^ (sr & 7)) * 8;

    auto stagePA = [&](int p, int g, int t) {
        const long kc = (long)t * 64;
        const bf16* src = A + (baseM + g * 64 + sr) * (long)lda + kc + sgc;
        __builtin_amdgcn_global_load_lds(GLOBAL_AS(src),
            LDS_AS(&As[p][0][g * 4096 + wave * 512]), 16, 0, 0);
        __builtin_amdgcn_global_load_lds(GLOBAL_AS(src + 128 * (long)lda),
            LDS_AS(&As[p][1][g * 4096 + wave * 512]), 16, 0, 0);
    };
    auto stagePBu = [&](int p, int u, int t) {
        const long kc = (long)t * 64;
        const bf16* src = B + (baseN + u * 64 + sr) * (long)ldb + kc + sgc;
        __builtin_amdgcn_global_load_lds(GLOBAL_AS(src),
            LDS_AS(&Bs[p][u * 4096 + wave * 512]), 16, 0, 0);
    };

    floatx4 acc[8][3] = {};   // [mf 0..7][nf 0..2]
    bf16x8 af0[4][2], af1[4][2], bf01[2][2], bf2[2];

    auto rdAf0 = [&](int p) {
        #pragma unroll
        for (int mf = 0; mf < 4; ++mf)
            #pragma unroll
            for (int ks = 0; ks < 2; ++ks) {
                const int r = mf * 16 + l16;
                af0[mf][ks] = *(const bf16x8*)(&As[p][wm][r * 64 + (((ks * 4 + quad) ^ (r & 7)) * 8)]);
            }
    };
    auto rdAf1 = [&](int p) {
        #pragma unroll
        for (int mf = 0; mf < 4; ++mf)
            #pragma unroll
            for (int ks = 0; ks < 2; ++ks) {
                const int r = 64 + mf * 16 + l16;
                af1[mf][ks] = *(const bf16x8*)(&As[p][wm][r * 64 + (((ks * 4 + quad) ^ (r & 7)) * 8)]);
            }
    };
    auto rdB01 = [&](int p) {
        #pragma unroll
        for (int nf = 0; nf < 2; ++nf)
            #pragma unroll
            for (int ks = 0; ks < 2; ++ks) {
                const int r = wn * 48 + nf * 16 + l16;
                bf01[nf][ks] = *(const bf16x8*)(&Bs[p][r * 64 + (((ks * 4 + quad) ^ (r & 7)) * 8)]);
            }
    };
    auto rdB2 = [&](int p) {
        #pragma unroll
        for (int ks = 0; ks < 2; ++ks) {
            const int r = wn * 48 + 32 + l16;
            bf2[ks] = *(const bf16x8*)(&Bs[p][r * 64 + (((ks * 4 + quad) ^ (r & 7)) * 8)]);
        }
    };

    // 16 MFMA: af0 x B cols 0..31
    auto mmA0B01 = [&]() {
        __builtin_amdgcn_s_setprio(1);
        #pragma unroll
        for (int mf = 0; mf < 4; ++mf)
            #pragma unroll
            for (int nf = 0; nf < 2; ++nf)
                #pragma unroll
                for (int ks = 0; ks < 2; ++ks)
                    acc[mf][nf] = __builtin_amdgcn_mfma_f32_16x16x32_bf16(
                        af0[mf][ks], bf01[nf][ks], acc[mf][nf], 0, 0, 0);
        __builtin_amdgcn_s_setprio(0);
    };
    // 16 MFMA: (af0, then af1) x B cols 32..47 — af1's lgkm hides under af0 half
    auto mmB2 = [&]() {
        __builtin_amdgcn_s_setprio(1);
        #pragma unroll
        for (int mf = 0; mf < 4; ++mf)
            #pragma unroll
            for (int ks = 0; ks < 2; ++ks)
                acc[mf][2] = __builtin_amdgcn_mfma_f32_16x16x32_bf16(
                    af0[mf][ks], bf2[ks], acc[mf][2], 0, 0, 0);
        #pragma unroll
        for (int mf = 0; mf < 4; ++mf)
            #pragma unroll
            for (int ks = 0; ks < 2; ++ks)
                acc[4 + mf][2] = __builtin_amdgcn_mfma_f32_16x16x32_bf16(
                    af1[mf][ks], bf2[ks], acc[4 + mf][2], 0, 0, 0);
        __builtin_amdgcn_s_setprio(0);
    };
    // 16 MFMA: af1 x B cols 0..31
    auto mmA1B01 = [&]() {
        __builtin_amdgcn_s_setprio(1);
        #pragma unroll
        for (int mf = 0; mf < 4; ++mf)
            #pragma unroll
            for (int nf = 0; nf < 2; ++nf)
                #pragma unroll
                for (int ks = 0; ks < 2; ++ks)
                    acc[4 + mf][nf] = __builtin_amdgcn_mfma_f32_16x16x32_bf16(
                        af1[mf][ks], bf01[nf][ks], acc[4 + mf][nf], 0, 0, 0);
        __builtin_amdgcn_s_setprio(0);
    };

    // prologue: tile0 fully (7 loads); retire B+A-g0, leave PA1(t0) in flight
    stagePBu(0, 0, 0); stagePBu(0, 1, 0); stagePBu(0, 2, 0);
    stagePA(0, 0, 0);  stagePA(0, 1, 0);
    VMCNT(2);
    BARRIER();

    const int NT = K / 64;
    for (int t = 0; t < NT; ++t) {
        const int p = t & 1;
        const bool more = (t + 1 < NT);

        // ph1 — reads covered by prev ph3's vmcnt(2)+barrier (prologue for t=0)
        rdAf0(p); rdB01(p); rdB2(p);
        if (more) {
            stagePBu(p ^ 1, 0, t + 1); stagePBu(p ^ 1, 1, t + 1); stagePBu(p ^ 1, 2, t + 1);
            VMCNT(3);                 // retires t's PA1 (for ph2); keeps t+1's B in flight
        } else {
            VMCNT(0);
        }
        BARRIER(); SCHED();
        mmA0B01();
        BARRIER();

        // ph2 — rdAf1 covered by ph1's vmcnt(3)+barrier
        rdAf1(p);
        if (more) stagePA(p ^ 1, 0, t + 1);
        BARRIER(); SCHED();
        mmB2();
        BARRIER();

        // ph3 — no LDS reads; stage last unit, retire next ph1's inputs
        if (more) { stagePA(p ^ 1, 1, t + 1); VMCNT(2); }
        SCHED();
        mmA1B01();
        BARRIER();
    }

    #pragma unroll
    for (int i = 0; i < 8; ++i)
        #pragma unroll
        for (int j = 0; j < 3; ++j)
            #pragma unroll
            for (int r = 0; r < 4; ++r) {
                long row = baseM + wm * 128 + i * 16 + quad * 4 + r;
                long col = baseN + wn * 48 + j * 16 + l16;
                C[row * (long)N + col] = (bf16)acc[i][j][r];
            }
}

// ---------------------------------------------------------------------------
// gemm_db64: NT GEMM 128x128, 4 waves, BK=64, never-drain counted vmcnt at
// 2 blocks/CU. Split-K via blockIdx.z -> fp32 partials. (o-proj; proven R6.)
// ---------------------------------------------------------------------------
__global__ __launch_bounds__(256, 2) void gemm_db64(
    const bf16* __restrict__ A, const bf16* __restrict__ B,
    float* __restrict__ Cp, int N, int Kd, int lda, int ldb)
{
    __shared__ bf16 As[2][128 * 64];
    __shared__ bf16 Bs[2][128 * 64];

    const int tid  = threadIdx.x;
    const int wave = tid >> 6, lane = tid & 63;
    const int quad = lane >> 4, l16 = lane & 15;
    const int wm = (wave & 1) * 64, wn = (wave >> 1) * 64;
    const long baseM = (long)blockIdx.x * 128;
    const long baseN = (long)blockIdx.y * 128;
    const long koff  = (long)blockIdx.z * Kd;

    const int sr  = tid >> 3;
    const int sgc = ((tid & 7) ^ (sr & 7)) * 8;

    auto stage = [&](int p, int t) {
        const long kc = koff + (long)t * 64;
        #pragma unroll
        for (int u = 0; u < 4; ++u) {
            const bf16* sa = A + (baseM + u * 32 + sr) * (long)lda + kc + sgc;
            __builtin_amdgcn_global_load_lds(GLOBAL_AS(sa),
                LDS_AS(&As[p][u * 2048 + wave * 512]), 16, 0, 0);
        }
        #pragma unroll
        for (int u = 0; u < 4; ++u) {
            const bf16* sb = B + (baseN + u * 32 + sr) * (long)ldb + kc + sgc;
            __builtin_amdgcn_global_load_lds(GLOBAL_AS(sb),
                LDS_AS(&Bs[p][u * 2048 + wave * 512]), 16, 0, 0);
        }
    };

    floatx4 acc[4][4] = {};

    stage(0, 0);

    const int NT = Kd / 64;
    int cur = 0;
    for (int t = 0; t < NT; ++t) {
        if (t + 1 < NT) { stage(cur ^ 1, t + 1); VMCNT(8); }
        else            { VMCNT(0); }
        BARRIER();

        bf16x8 af[4][2], bfr[4][2];
        #pragma unroll
        for (int i = 0; i < 4; ++i)
            #pragma unroll
            for (int ks = 0; ks < 2; ++ks) {
                const int r = wm + i * 16 + l16;
                af[i][ks] = *(const bf16x8*)(&As[cur][r * 64 + (((ks * 4 + quad) ^ (r & 7)) * 8)]);
            }
        #pragma unroll
        for (int j = 0; j < 4; ++j)
            #pragma unroll
            for (int ks = 0; ks < 2; ++ks) {
                const int r = wn + j * 16 + l16;
                bfr[j][ks] = *(const bf16x8*)(&Bs[cur][r * 64 + (((ks * 4 + quad) ^ (r & 7)) * 8)]);
            }

        __builtin_amdgcn_s_setprio(1);
        #pragma unroll
        for (int i = 0; i < 4; ++i)
            #pragma unroll
            for (int j = 0; j < 4; ++j)
                #pragma unroll
                for (int ks = 0; ks < 2; ++ks)
                    acc[i][j] = __builtin_amdgcn_mfma_f32_16x16x32_bf16(
                        af[i][ks], bfr[j][ks], acc[i][j], 0, 0, 0);
        __builtin_amdgcn_s_setprio(0);

        BARRIER();
        cur ^= 1;
    }

    const long Mrows = (long)gridDim.x * 128;
    float* C = Cp + (long)blockIdx.z * Mrows * N;
    #pragma unroll
    for (int i = 0; i < 4; ++i)
        #pragma unroll
        for (int j = 0; j < 4; ++j)
            #pragma unroll
            for (int r = 0; r < 4; ++r) {
                long row = baseM + wm + i * 16 + quad * 4 + r;
                long col = baseN + wn + j * 16 + l16;
                C[row * (long)N + col] = acc[i][j][r];
            }
}

// ---------------------------------------------------------------------------
// reduce2: out = P0 + P1, cast per flag. HBM-bound.
// ---------------------------------------------------------------------------
__global__ __launch_bounds__(256) void reduce2(
    const float* __restrict__ P0, const float* __restrict__ P1,
    void* __restrict__ out, const int* flagp)
{
    long i = ((long)blockIdx.x * 256 + threadIdx.x) * 4;
    floatx4 a = *(const floatx4*)(P0 + i);
    floatx4 b = *(const floatx4*)(P1 + i);
    floatx4 s = a + b;
    if (*flagp) {
        bf16x4 o;
        #pragma unroll
        for (int r = 0; r < 4; ++r) o[r] = (bf16)s[r];
        *(bf16x4*)((bf16*)out + i) = o;
    } else {
        *(floatx4*)((float*)out + i) = s;
    }
}

// ---------------------------------------------------------------------------
// In-place RMSNorm + RoPE on q/k sections of qkv[t][6144].
// ---------------------------------------------------------------------------
__global__ __launch_bounds__(256) void qkv_post(
    bf16* __restrict__ qkv, const int* __restrict__ positions,
    const bf16* __restrict__ qnw, const bf16* __restrict__ knw)
{
    const int t = blockIdx.x;
    const int tid = threadIdx.x, wave = tid >> 6, lane = tid & 63;
    const float pos = (float)positions[t];

    const float inv = expf(-(float)lane * (float)(9.210340371976184 / 64.0));
    float sn, cs;
    sincosf(pos * inv, &sn, &cs);

    bf16* row = qkv + (long)t * QKV_N;

    for (int u = wave; u < 40; u += 4) {
        bf16* p       = (u < 32) ? row + u * HD : row + Q_SIZE + (u - 32) * HD;
        const bf16* w = (u < 32) ? qnw : knw;
        float x1 = (float)p[lane], x2 = (float)p[lane + 64];
        float ss = x1 * x1 + x2 * x2;
        #pragma unroll
        for (int m = 32; m; m >>= 1) ss += __shfl_xor(ss, m);
        float rr = rsqrtf(ss * (1.f / 128.f) + 1e-6f);
        float y1 = x1 * rr * (float)w[lane];
        float y2 = x2 * rr * (float)w[lane + 64];
        p[lane]      = (bf16)(y1 * cs - y2 * sn);
        p[lane + 64] = (bf16)(y2 * cs + y1 * sn);
    }
}

// ---------------------------------------------------------------------------
// V transpose: vt[kvh][d][t] from qkv[t][5120+kvh*128+d].
// ---------------------------------------------------------------------------
__global__ __launch_bounds__(256) void vtrans(const bf16* __restrict__ qkv,
                                              bf16* __restrict__ vt)
{
    __shared__ bf16 tile[64][136];
    const int t0 = blockIdx.x * 64, kvh = blockIdx.y, tid = threadIdx.x;

    const int rl = tid >> 4, c8 = (tid & 15) * 8;
    const bf16* src = qkv + (long)t0 * QKV_N + 5120 + kvh * HD;
    #pragma unroll
    for (int it = 0; it < 4; ++it) {
        int r = it * 16 + rl;
        *(bf16x8*)(&tile[r][c8]) = *(const bf16x8*)(src + (long)r * QKV_N + c8);
    }
    __syncthreads();

    const int d = tid >> 1, tb = (tid & 1) * 32;
    bf16* dst = vt + ((long)kvh * HD + d) * T_SEQ + t0 + tb;
    #pragma unroll
    for (int it = 0; it < 4; ++it) {
        bf16x8 v;
        #pragma unroll
        for (int j = 0; j < 8; ++j) v[j] = tile[tb + it * 8 + j][d];
        *(bf16x8*)(dst + it * 8) = v;
    }
}

// ---------------------------------------------------------------------------
// attn5: unpaired 64-row q-tiles, grid (head, 32) with iq = 31 - blockIdx.y
// (LPT). 1024 blocks; LDS 48KB -> 3 blocks/CU. Counted vmcnt(4) mid-iter
// keeps the K[t+1] prefetch in flight. P fully in-register via sigma'd K
// staging + v_cvt_pk_bf16_f32 + permlane32_swap.
// ---------------------------------------------------------------------------
__global__ __launch_bounds__(256, 3) void attn5(bf16* qkv, const bf16* __restrict__ vt)
{
    __shared__ bf16 Ks[2][64 * 128];   // [kt-row][d], 16B chunk c at c^(row&15), rows sigma'd
    __shared__ bf16 Vs[128 * 64];      // [d][kt-row], 16B chunk c at c^(d&7), single buffer

    const int tid  = threadIdx.x, wave = tid >> 6, lane = tid & 63;
    const int quad = lane >> 4, l16 = lane & 15;
    const int h = blockIdx.x, kvh = h >> 2;
    const int iq = 31 - blockIdx.y;    // tile index, longest first (LPT)
    const int q0 = iq * 64;

    const float C1 = 0.12753236f;      // 128^-0.5 * log2(e)
    const float C2 = 17.312340f;       // 12 * log2(e)

    bf16x8 qf[4];
    {
        const bf16* qa = qkv + (long)(q0 + wave * 16 + l16) * QKV_N + h * HD + quad * 8;
        #pragma unroll
        for (int ks = 0; ks < 4; ++ks) qf[ks] = *(const bf16x8*)(qa + ks * 32);
    }

    floatx4 oacc[8] = {};
    float ls = 0.f;

    const int krl = lane >> 4, kc = lane & 15;
    const int vrl = lane >> 3, vc = lane & 7;
    const int kswz = (kc ^ (wave * 4 + krl)) * 8;
    const int vswz = (vc ^ (vrl & 7)) * 8;
    const int wsig = ((wave & 1) << 1) | (wave >> 1);           // sigma(wave): 1<->2
    const int sq4  = (((quad & 1) << 1) | (quad >> 1)) << 2;    // sigma(quad)*4

    const bf16* kg0 = qkv + Q_SIZE + kvh * HD;
    const bf16* vg0 = vt + (long)kvh * HD * T_SEQ;

    auto stageK = [&](int p, int kt) {
        const bf16* kg = kg0 + (long)(kt * 64) * QKV_N;
        #pragma unroll
        for (int it = 0; it < 4; ++it) {
            const int rK = it * 16 + wsig * 4 + krl;
            __builtin_amdgcn_global_load_lds(GLOBAL_AS(kg + (long)rK * QKV_N + kswz),
                                             LDS_AS(&Ks[p][it * 2048 + wave * 512]), 16, 0, 0);
        }
    };
    auto stageV = [&](int kt) {
        const bf16* vg = vg0 + kt * 64;
        #pragma unroll
        for (int it = 0; it < 4; ++it) {
            const int dV = it * 32 + wave * 8 + vrl;
            __builtin_amdgcn_global_load_lds(GLOBAL_AS(vg + (long)dV * T_SEQ + vswz),
                                             LDS_AS(&Vs[it * 2048 + wave * 512]), 16, 0, 0);
        }
    };

    stageK(0, 0);

    const int qg = q0 + wave * 16 + l16;

    for (int kt = 0; kt <= iq; ++kt) {
        const int p = kt & 1;
        __syncthreads();                   // K[p] landed (vmcnt0); all Vs readers done
        stageV(kt);                        // V first (counted-wait relies on FIFO retire)
        if (kt < iq) stageK(p ^ 1, kt + 1);

        const int k0 = kt * 64;

        floatx4 sT[4] = {};
        #pragma unroll
        for (int j2 = 0; j2 < 4; ++j2)
            #pragma unroll
            for (int ks = 0; ks < 4; ++ks) {
                bf16x8 kf = *(const bf16x8*)(&Ks[p][(j2 * 16 + l16) * 128 + (((ks * 4 + quad) ^ l16) * 8)]);
                sT[j2] = __builtin_amdgcn_mfma_f32_16x16x32_bf16(kf, qf[ks], sT[j2], 0, 0, 0);
            }

        const bool diag = (kt == iq);
        unsigned lov[4], hiv[4];
        #pragma unroll
        for (int j2 = 0; j2 < 4; ++j2) {
            float ev[4];
            #pragma unroll
            for (int r = 0; r < 4; ++r) {
                float x = __builtin_amdgcn_exp2f(sT[j2][r] * C1 - C2);
                if (diag && (k0 + j2 * 16 + sq4 + r > qg)) x = 0.f;
                ls += x;
                ev[r] = x;
            }
            asm("v_cvt_pk_bf16_f32 %0, %1, %2" : "=v"(lov[j2]) : "v"(ev[0]), "v"(ev[1]));
            asm("v_cvt_pk_bf16_f32 %0, %1, %2" : "=v"(hiv[j2]) : "v"(ev[2]), "v"(ev[3]));
        }

        bf16x8 pa[2];
        #pragma unroll
        for (int ks2 = 0; ks2 < 2; ++ks2) {
            auto wl = __builtin_amdgcn_permlane32_swap(lov[2 * ks2], lov[2 * ks2 + 1], false, false);
            auto wh = __builtin_amdgcn_permlane32_swap(hiv[2 * ks2], hiv[2 * ks2 + 1], false, false);
            union { unsigned w[4]; bf16x8 v; } u;
            u.w[0] = wl[0]; u.w[1] = wh[0]; u.w[2] = wl[1]; u.w[3] = wh[1];
            pa[ks2] = u.v;
        }

        if (kt < iq) asm volatile("s_waitcnt vmcnt(4)" ::: "memory");
        else         asm volatile("s_waitcnt vmcnt(0)" ::: "memory");
        __builtin_amdgcn_s_barrier();
        __builtin_amdgcn_sched_barrier(0);

        #pragma unroll
        for (int ks2 = 0; ks2 < 2; ++ks2)
            #pragma unroll
            for (int vj = 0; vj < 8; ++vj) {
                const int d = vj * 16 + l16;
                bf16x8 vb = *(const bf16x8*)(&Vs[d * 64 + (((ks2 * 4 + quad) ^ (d & 7)) * 8)]);
                oacc[vj] = __builtin_amdgcn_mfma_f32_16x16x32_bf16(pa[ks2], vb, oacc[vj], 0, 0, 0);
            }
    }

    ls += __shfl_xor(ls, 16); ls += __shfl_xor(ls, 32);
    float rinv[4];
    #pragma unroll
    for (int r = 0; r < 4; ++r) rinv[r] = 1.f / __shfl(ls, quad * 4 + r);

    #pragma unroll
    for (int vj = 0; vj < 8; ++vj)
        #pragma unroll
        for (int r = 0; r < 4; ++r) {
            const long row = q0 + wave * 16 + quad * 4 + r;
            qkv[row * (long)QKV_N + h * HD + vj * 16 + l16] = (bf16)(oacc[vj][r] * rinv[r]);
        }
}

// ---------------------------------------------------------------------------
extern "C" void kernel_launch(void* const* d_in, const int* in_sizes, int n_in,
                              void* d_out, int out_size, void* d_ws, size_t ws_size,
                              hipStream_t stream)
{
    const int* positions = (const int*)d_in[0];

    char* ws = (char*)d_ws;
    bf16* qkv  = (bf16*)(ws);              // [2048][6144]  25165824 B
    bf16* hb   = (bf16*)(ws + 25165824);   // [2048][2048]   8388608 B (dead after gemm1)
    bf16* vt   = hb;                       // [8][128][2048] 4194304 B (aliases hb)
    // o-proj split-K partials: live only after attn5 (hb/vt and wqb both dead)
    float* P0  = (float*)(ws + 25165824);  // [2048][2048] fp32 16777216 B
    float* P1  = (float*)(ws + 41943040);  // [2048][2048] fp32 16777216 B (ends at wob)
    bf16* wqb  = (bf16*)(ws + 33554432);   // [6144][2048]  25165824 B
    bf16* wob  = (bf16*)(ws + 58720256);   // [2048][4096]  16777216 B
    bf16* qnb  = (bf16*)(ws + 75497472);
    bf16* knb  = (bf16*)(ws + 75497728);
    int*  flag = (int*) (ws + 75497984);

    detect_dtype<<<dim3(1), dim3(64), 0, stream>>>((const unsigned short*)d_in[2], flag);
    convert_all<<<dim3(12289), dim3(256), 0, stream>>>(
        d_in[1], d_in[2], d_in[3], d_in[4], d_in[5],
        hb, wqb, wob, qnb, knb, flag);

    // QKV proj: 256x192 3-phase dbuf tiles, grid (32, 8) = 256 blocks (full chip).
    gemm3p<<<dim3(QKV_N / 192, T_SEQ / 256), dim3(512), 0, stream>>>(
        hb, wqb, qkv, QKV_N, HIDDEN, HIDDEN, HIDDEN);
    vtrans<<<dim3(T_SEQ / 64, NUM_KV), dim3(256), 0, stream>>>(qkv, vt);
    qkv_post<<<dim3(T_SEQ), dim3(256), 0, stream>>>(qkv, positions, qnb, knb);
    attn5<<<dim3(NUM_H, 32), dim3(256), 0, stream>>>(qkv, vt);
    // o-proj: split-K=2, 128x128 BK=64 never-drain dbuf, 512 blocks = 2/CU.
    gemm_db64<<<dim3(T_SEQ / 128, HIDDEN / 128, 2), dim3(256), 0, stream>>>(
        qkv, wob, P0, HIDDEN, Q_SIZE / 2, QKV_N, Q_SIZE);
    reduce2<<<dim3(4096), dim3(256), 0, stream>>>(P0, P1, d_out, flag);
}